// Round 4
// baseline (5198.312 us; speedup 1.0000x reference)
//
#include <hip/hip_runtime.h>
#include <hip/hip_bf16.h>
#include <cmath>

typedef __hip_bfloat16 bf16;
#define DEV static __device__ __forceinline__

DEV float bf2f(bf16 x) { return __bfloat162float(x); }
DEV bf16  f2bf(float x) { return __float2bfloat16(x); }
DEV float bfraw2f(unsigned int h) { return __uint_as_float(h << 16); }

constexpr int B_  = 64, N_ = 197, C_ = 768, H_ = 12, HD_ = 64;
constexpr int C3_ = 3 * C_;      // 2304
constexpr int C4_ = 4 * C_;      // 3072
constexpr int M_  = B_ * N_;     // 12608
constexpr int BH_ = B_ * H_;     // 768
constexpr int NM1 = N_ - 1;      // 196

// ---------------- dtype detection ----------------
// fp32 data viewed as halfwords: ~44% of (random-mantissa) low halfwords have
// bf16-exponent >= 143; genuine bf16 of ~0.02*N(0,1) never does.
__global__ __launch_bounds__(256) void detect_kernel(const unsigned short* __restrict__ w,
                                                     int* __restrict__ flag) {
    __shared__ int cnt;
    if (threadIdx.x == 0) cnt = 0;
    __syncthreads();
    int c = 0;
#pragma unroll
    for (int k = 0; k < 8; ++k) {
        unsigned short u = w[threadIdx.x * 8 + k];
        int e = (u >> 7) & 0xFF;
        if (e >= 143) ++c;
    }
    atomicAdd(&cnt, c);
    __syncthreads();
    if (threadIdx.x == 0) *flag = (cnt >= 8) ? 1 : 0;   // 1 = fp32 inputs
}

DEV float load_in(const void* p, size_t i, bool f32) {
    return f32 ? ((const float*)p)[i] : bf2f(((const bf16*)p)[i]);
}

// ---------------- converters (flag-dispatched) ----------------
__global__ __launch_bounds__(256) void cvt32_kernel(const void* __restrict__ s, float* __restrict__ d,
                                                    int n, const int* __restrict__ flag) {
    const bool f32 = (*flag != 0);
    int i = blockIdx.x * 256 + threadIdx.x, st = gridDim.x * 256;
    for (; i < n; i += st) d[i] = load_in(s, i, f32);
}
__global__ __launch_bounds__(256) void cvt64_kernel(const void* __restrict__ s, double* __restrict__ d,
                                                    int n, const int* __restrict__ flag) {
    const bool f32 = (*flag != 0);
    int i = blockIdx.x * 256 + threadIdx.x, st = gridDim.x * 256;
    for (; i < n; i += st) d[i] = (double)load_in(s, i, f32);
}
__global__ __launch_bounds__(256) void zero64_kernel(double* __restrict__ d, int n) {
    int i = blockIdx.x * 256 + threadIdx.x, st = gridDim.x * 256;
    for (; i < n; i += st) d[i] = 0.0;
}

// ---------------- block reductions ----------------
DEV double bred_sum64(double v, double* red) {
    int t = threadIdx.x; red[t] = v; __syncthreads();
    for (int s = 128; s > 0; s >>= 1) { if (t < s) red[t] += red[t + s]; __syncthreads(); }
    double r = red[0]; __syncthreads(); return r;
}
DEV double bred_max64(double v, double* red) {
    int t = threadIdx.x; red[t] = v; __syncthreads();
    for (int s = 128; s > 0; s >>= 1) { if (t < s) red[t] = fmax(red[t], red[t + s]); __syncthreads(); }
    double r = red[0]; __syncthreads(); return r;
}
DEV double bred_min64(double v, double* red) {
    int t = threadIdx.x; red[t] = v; __syncthreads();
    for (int s = 128; s > 0; s >>= 1) { if (t < s) red[t] = fmin(red[t], red[t + s]); __syncthreads(); }
    double r = red[0]; __syncthreads(); return r;
}
DEV float bred_sum32(float v, float* red) {
    int t = threadIdx.x; red[t] = v; __syncthreads();
    for (int s = 128; s > 0; s >>= 1) { if (t < s) red[t] += red[t + s]; __syncthreads(); }
    float r = red[0]; __syncthreads(); return r;
}
DEV float bred_max32(float v, float* red) {
    int t = threadIdx.x; red[t] = v; __syncthreads();
    for (int s = 128; s > 0; s >>= 1) { if (t < s) red[t] = fmaxf(red[t], red[t + s]); __syncthreads(); }
    float r = red[0]; __syncthreads(); return r;
}

// ---------------- LN1 fp64: raw x -> xn64 ----------------
__global__ __launch_bounds__(256) void ln64_kernel(const void* __restrict__ in,
                                                   const double* __restrict__ g,
                                                   const double* __restrict__ bb,
                                                   double* __restrict__ out,
                                                   const int* __restrict__ flag) {
    __shared__ double red[256];
    const bool f32 = (*flag != 0);
    const int tid = threadIdx.x;
    const size_t row = blockIdx.x;
    double x0 = (double)load_in(in, row * C_ + tid, f32);
    double x1 = (double)load_in(in, row * C_ + tid + 256, f32);
    double x2 = (double)load_in(in, row * C_ + tid + 512, f32);
    double m = bred_sum64(x0 + x1 + x2, red) / 768.0;
    double d0 = x0 - m, d1 = x1 - m, d2 = x2 - m;
    double var = bred_sum64(d0 * d0 + d1 * d1 + d2 * d2, red) / 768.0;
    double istd = 1.0 / sqrt(var + 1e-5);
    double* op = out + row * C_;
    op[tid]     = (d0 * istd) * g[tid]     + bb[tid];
    op[tid+256] = (d1 * istd) * g[tid+256] + bb[tid+256];
    op[tid+512] = (d2 * istd) * g[tid+512] + bb[tid+512];
}

// ---------------- LN2 fp32 ----------------
__global__ __launch_bounds__(256) void ln32_kernel(const float* __restrict__ in,
                                                   const float* __restrict__ g,
                                                   const float* __restrict__ bb,
                                                   float* __restrict__ out) {
    __shared__ float red[256];
    const int tid = threadIdx.x;
    const size_t row = blockIdx.x;
    const float* xp = in + row * C_;
    float x0 = xp[tid], x1 = xp[tid + 256], x2 = xp[tid + 512];
    float m = bred_sum32(x0 + x1 + x2, red) * (1.0f / 768.0f);
    float d0 = x0 - m, d1 = x1 - m, d2 = x2 - m;
    float var = bred_sum32(d0 * d0 + d1 * d1 + d2 * d2, red) * (1.0f / 768.0f);
    float istd = 1.0f / sqrtf(var + 1e-5f);
    float* op = out + row * C_;
    op[tid]     = d0 * istd * g[tid]     + bb[tid];
    op[tid+256] = d1 * istd * g[tid+256] + bb[tid+256];
    op[tid+512] = d2 * istd * g[tid+512] + bb[tid+512];
}

// ---------------- q0: fp64 q of token 0, policy folded ----------------
__global__ __launch_bounds__(256) void q0_kernel(const double* __restrict__ xn64,
                                                 const double* __restrict__ w64,
                                                 const double* __restrict__ pol,
                                                 double* __restrict__ q0) {
    const int b = blockIdx.x, tid = threadIdx.x;
    const double* xr = xn64 + (size_t)(b * N_) * C_;
    double p0 = pol[b * N_];
    for (int j = tid; j < C_; j += 256) {
        double acc = 0.0;
        for (int c = 0; c < C_; ++c) acc += xr[c] * w64[(size_t)c * C3_ + j];
        q0[(size_t)b * C_ + j] = acc * p0;
    }
}

// ---------------- wq0[b,h,c] = sum_d Wk[c, 768+h*64+d] * q0[b,h,d] ----------------
__global__ __launch_bounds__(256) void wq0_kernel(const double* __restrict__ w64,
                                                  const double* __restrict__ q0,
                                                  double* __restrict__ wq0) {
    const int b = blockIdx.x, tid = threadIdx.x;
    for (int idx = tid; idx < H_ * C_; idx += 256) {
        int h = idx / C_, c = idx - h * C_;
        const double* wr = w64 + (size_t)c * C3_ + C_ + h * HD_;
        const double* qr = q0 + (size_t)b * C_ + h * HD_;
        double acc = 0.0;
#pragma unroll 8
        for (int d = 0; d < HD_; ++d) acc += wr[d] * qr[d];
        wq0[((size_t)b * H_ + h) * C_ + c] = acc;
    }
}

// ---------------- cls row: fp64 softmax of (xn64 . wq0)*pol*0.125 ----------------
__global__ __launch_bounds__(256) void cls_kernel(const double* __restrict__ xn64,
                                                  const double* __restrict__ wq0,
                                                  const double* __restrict__ pol,
                                                  double* __restrict__ cls) {
    __shared__ double red[256];
    const int bh = blockIdx.x, b = bh / H_;
    const int tid = threadIdx.x;
    const double* wr = wq0 + (size_t)bh * C_;
    double s = -INFINITY;
    if (tid < N_) {
        const double* xr = xn64 + (size_t)(b * N_ + tid) * C_;
        double acc = 0.0;
#pragma unroll 4
        for (int c = 0; c < C_; ++c) acc += xr[c] * wr[c];
        s = acc * pol[b * N_ + tid] * 0.125;
    }
    double mx = bred_max64(s, red);
    double a = 0.0;
    if (tid < N_) {
        double p = pol[b * N_ + tid];
        double ap = p + (1.0 - p) * ((tid == 0) ? 1.0 : 0.0);
        a = exp(s - mx) * ap;
    }
    double ssum = bred_sum64(a, red);
    if (tid < N_) cls[(size_t)bh * N_ + tid] = (a + 1e-6 / 197.0) / (ssum + 1e-6);
}

// ---------------- fp64 GEMM for V: 64x64 tile, 4x4 micro ----------------
__global__ __launch_bounds__(256) void gemm64_v(const double* __restrict__ A,
                                                const double* __restrict__ W,
                                                const double* __restrict__ pol,
                                                float* __restrict__ v32,
                                                double* __restrict__ vnorm2) {
    __shared__ double As[16][65];
    __shared__ double Bs[16][68];
    const int tid = threadIdx.x;
    const int tx = tid & 15, ty = tid >> 4;
    const int bx = blockIdx.x, by = blockIdx.y;
    const int arow = tid & 63, ak = (tid >> 6) * 4;
    const int brow = tid >> 4, bcol = (tid & 15) * 4;

    double acc[4][4];
#pragma unroll
    for (int i = 0; i < 4; ++i)
#pragma unroll
        for (int j = 0; j < 4; ++j) acc[i][j] = 0.0;

    const int gr = by * 64 + arow;          // M_ = 12608 = 197*64, always in range
    for (int k0 = 0; k0 < C_; k0 += 16) {
        const double* ap = A + (size_t)gr * C_ + k0 + ak;
        double a0 = ap[0], a1 = ap[1], a2 = ap[2], a3 = ap[3];
        const double* bp = W + (size_t)(k0 + brow) * C3_ + 2 * C_ + bx * 64 + bcol;
        double b0 = bp[0], b1 = bp[1], b2 = bp[2], b3 = bp[3];
        __syncthreads();
        As[ak + 0][arow] = a0; As[ak + 1][arow] = a1; As[ak + 2][arow] = a2; As[ak + 3][arow] = a3;
        Bs[brow][bcol + 0] = b0; Bs[brow][bcol + 1] = b1; Bs[brow][bcol + 2] = b2; Bs[brow][bcol + 3] = b3;
        __syncthreads();
#pragma unroll
        for (int kk = 0; kk < 16; ++kk) {
            double aa[4], bb[4];
#pragma unroll
            for (int i = 0; i < 4; ++i) aa[i] = As[kk][ty * 4 + i];
#pragma unroll
            for (int j = 0; j < 4; ++j) bb[j] = Bs[kk][tx * 4 + j];
#pragma unroll
            for (int i = 0; i < 4; ++i)
#pragma unroll
                for (int j = 0; j < 4; ++j) acc[i][j] += aa[i] * bb[j];
        }
    }
    const int col0 = bx * 64 + tx * 4;
    const int h = col0 >> 6, d0 = col0 & 63;
#pragma unroll
    for (int i = 0; i < 4; ++i) {
        int row = by * 64 + ty * 4 + i;
        int b = row / N_, nn = row - b * N_;
        double p = pol[row];
        double s2 = 0.0;
        float* dst = v32 + (((size_t)(b * H_ + h)) * N_ + nn) * HD_ + d0;
#pragma unroll
        for (int j = 0; j < 4; ++j) {
            double vv = acc[i][j] * p;
            dst[j] = (float)vv;
            s2 += vv * vv;
        }
        atomicAdd(&vnorm2[row], s2);
    }
}

// ---------------- fp32 GEMM for Q,K: 128x128 tile ----------------
__global__ __launch_bounds__(256) void gemm_qk32(const double* __restrict__ A64,
                                                 const double* __restrict__ W64,
                                                 const double* __restrict__ pol,
                                                 float* __restrict__ q32,
                                                 float* __restrict__ k32) {
    __shared__ float As[16][128];
    __shared__ float Bs[16][132];
    const int tid = threadIdx.x;
    const int tx = tid & 15, ty = tid >> 4;
    const int bx = blockIdx.x, by = blockIdx.y;
    const int arow = tid >> 1, ak0 = (tid & 1) * 8;
    const int brow = tid >> 4, bcol = (tid & 15) * 8;

    float acc[8][8];
#pragma unroll
    for (int i = 0; i < 8; ++i)
#pragma unroll
        for (int j = 0; j < 8; ++j) acc[i][j] = 0.f;

    const int gr = by * 128 + arow;
    for (int k0 = 0; k0 < C_; k0 += 16) {
        float av[8], bv[8];
        if (gr < M_) {
            const double* ap = A64 + (size_t)gr * C_ + k0 + ak0;
#pragma unroll
            for (int j = 0; j < 8; ++j) av[j] = (float)ap[j];
        } else {
#pragma unroll
            for (int j = 0; j < 8; ++j) av[j] = 0.f;
        }
        const double* bp = W64 + (size_t)(k0 + brow) * C3_ + bx * 128 + bcol;
#pragma unroll
        for (int j = 0; j < 8; ++j) bv[j] = (float)bp[j];
        __syncthreads();
#pragma unroll
        for (int j = 0; j < 8; ++j) As[ak0 + j][arow] = av[j];
#pragma unroll
        for (int j = 0; j < 8; ++j) Bs[brow][bcol + j] = bv[j];
        __syncthreads();
#pragma unroll
        for (int kk = 0; kk < 16; ++kk) {
            float4 a0 = *(const float4*)&As[kk][ty * 8];
            float4 a1 = *(const float4*)&As[kk][ty * 8 + 4];
            float4 b0 = *(const float4*)&Bs[kk][tx * 8];
            float4 b1 = *(const float4*)&Bs[kk][tx * 8 + 4];
            float aa[8] = {a0.x,a0.y,a0.z,a0.w,a1.x,a1.y,a1.z,a1.w};
            float bb[8] = {b0.x,b0.y,b0.z,b0.w,b1.x,b1.y,b1.z,b1.w};
#pragma unroll
            for (int i = 0; i < 8; ++i)
#pragma unroll
                for (int j = 0; j < 8; ++j) acc[i][j] += aa[i] * bb[j];
        }
    }
    const int row0 = by * 128 + ty * 8;
    const int col0 = bx * 128 + tx * 8;           // [0,1536)
    const int comp = col0 >= C_ ? 1 : 0;
    const int rem = col0 - comp * C_;
    const int h = rem >> 6, d0 = rem & 63;
    float* dstbase = comp ? k32 : q32;
#pragma unroll
    for (int i = 0; i < 8; ++i) {
        int row = row0 + i; if (row >= M_) break;
        int b = row / N_, nn = row - b * N_;
        float pv = (float)pol[row];
        float* dst = dstbase + (((size_t)(b * H_ + h)) * N_ + nn) * HD_ + d0;
#pragma unroll
        for (int j = 0; j < 8; ++j) dst[j] = acc[i][j] * pv;
    }
}

// ---------------- fp32 GEMM epilogue variants (proj/fc1/fc2) ----------------
struct Epi {
    const float* bias;
    const int* srctok;
    const void* xin;       // raw input x (dtype per flag)
    float* x2out;
    bf16* act;
    const float* x2in;
    void* dout;
    const int* flagp;
};

// MODE: 1 = proj -> x2 (+sel_x, *pol), 2 = fc1 -> gelu -> act(bf16), 3 = fc2 -> out (dtype per flag)
template <int MODE, typename TA>
__global__ __launch_bounds__(256) void gemm_k(const TA* __restrict__ A,
                                              const float* __restrict__ Bw,
                                              int M, int Nn, int K, Epi ep) {
    __shared__ float As[16][128];
    __shared__ float Bs[16][132];
    const int tid = threadIdx.x;
    const int tx = tid & 15, ty = tid >> 4;
    const int bx = blockIdx.x, by = blockIdx.y;
    const int arow = tid >> 1, ak0 = (tid & 1) * 8;
    const int brow = tid >> 4, bcol = (tid & 15) * 8;

    float acc[8][8];
#pragma unroll
    for (int i = 0; i < 8; ++i)
#pragma unroll
        for (int j = 0; j < 8; ++j) acc[i][j] = 0.f;

    const int gr = by * 128 + arow;
    for (int k0 = 0; k0 < K; k0 += 16) {
        float av[8];
        if (gr < M) {
            const TA* ap = A + (size_t)gr * K + k0 + ak0;
            if constexpr (sizeof(TA) == 4) {
                const float4* p4 = (const float4*)ap;
                float4 t0 = p4[0], t1 = p4[1];
                av[0]=t0.x; av[1]=t0.y; av[2]=t0.z; av[3]=t0.w;
                av[4]=t1.x; av[5]=t1.y; av[6]=t1.z; av[7]=t1.w;
            } else {
                uint4 u = *(const uint4*)ap;
                av[0]=bfraw2f(u.x & 0xffffu); av[1]=bfraw2f(u.x >> 16);
                av[2]=bfraw2f(u.y & 0xffffu); av[3]=bfraw2f(u.y >> 16);
                av[4]=bfraw2f(u.z & 0xffffu); av[5]=bfraw2f(u.z >> 16);
                av[6]=bfraw2f(u.w & 0xffffu); av[7]=bfraw2f(u.w >> 16);
            }
        } else {
#pragma unroll
            for (int j = 0; j < 8; ++j) av[j] = 0.f;
        }
        const float* bp = Bw + (size_t)(k0 + brow) * Nn + bx * 128 + bcol;
        float4 u0 = ((const float4*)bp)[0];
        float4 u1 = ((const float4*)bp)[1];
        __syncthreads();
#pragma unroll
        for (int j = 0; j < 8; ++j) As[ak0 + j][arow] = av[j];
        Bs[brow][bcol+0]=u0.x; Bs[brow][bcol+1]=u0.y; Bs[brow][bcol+2]=u0.z; Bs[brow][bcol+3]=u0.w;
        Bs[brow][bcol+4]=u1.x; Bs[brow][bcol+5]=u1.y; Bs[brow][bcol+6]=u1.z; Bs[brow][bcol+7]=u1.w;
        __syncthreads();
#pragma unroll
        for (int kk = 0; kk < 16; ++kk) {
            float4 a0 = *(const float4*)&As[kk][ty * 8];
            float4 a1 = *(const float4*)&As[kk][ty * 8 + 4];
            float4 b0 = *(const float4*)&Bs[kk][tx * 8];
            float4 b1 = *(const float4*)&Bs[kk][tx * 8 + 4];
            float aa[8] = {a0.x,a0.y,a0.z,a0.w,a1.x,a1.y,a1.z,a1.w};
            float bb[8] = {b0.x,b0.y,b0.z,b0.w,b1.x,b1.y,b1.z,b1.w};
#pragma unroll
            for (int i = 0; i < 8; ++i)
#pragma unroll
                for (int j = 0; j < 8; ++j) acc[i][j] += aa[i] * bb[j];
        }
    }
    const int row0 = by * 128 + ty * 8;
    const int col0 = bx * 128 + tx * 8;

    if constexpr (MODE == 1) {
        const bool f32 = (*ep.flagp != 0);
#pragma unroll
        for (int i = 0; i < 8; ++i) {
            int row = row0 + i; if (row >= M) break;
            int st = ep.srctok[row];
            float polv = (st >= 0) ? 1.f : 0.f;
            int b = row / N_;
            size_t xbase = ((size_t)(b * N_ + (st < 0 ? 0 : st))) * C_ + col0;
            float* o = ep.x2out + (size_t)row * C_ + col0;
#pragma unroll
            for (int j = 0; j < 8; ++j) {
                float selx = (st >= 0) ? load_in(ep.xin, xbase + j, f32) : 0.f;
                o[j] = selx + (acc[i][j] + ep.bias[col0 + j]) * polv;
            }
        }
    } else if constexpr (MODE == 2) {
#pragma unroll
        for (int i = 0; i < 8; ++i) {
            int row = row0 + i; if (row >= M) break;
            bf16* o = ep.act + (size_t)row * C4_ + col0;
#pragma unroll
            for (int j = 0; j < 8; ++j) {
                float z = acc[i][j] + ep.bias[col0 + j];
                float gl = 0.5f * z * (1.0f + erff(z * 0.70710678118654752f));
                o[j] = f2bf(gl);
            }
        }
    } else {
        const bool f32out = (*ep.flagp != 0);
#pragma unroll
        for (int i = 0; i < 8; ++i) {
            int row = row0 + i; if (row >= M) break;
            int st = ep.srctok[row];
            float polv = (st >= 0) ? 1.f : 0.f;
            const float* x2r = ep.x2in + (size_t)row * C_ + col0;
            size_t obase = (size_t)row * C_ + col0;
#pragma unroll
            for (int j = 0; j < 8; ++j) {
                float hv = acc[i][j] + ep.bias[col0 + j];
                float val = (x2r[j] + hv) * polv;
                if (f32out) ((float*)ep.dout)[obase + j] = val;
                else        ((bf16*)ep.dout)[obase + j] = f2bf(val);
            }
        }
    }
}

// ---------------- fp32 attention probs (continuous path) ----------------
__global__ __launch_bounds__(256) void attn_kernel(const float* __restrict__ q,
                                                   const float* __restrict__ k,
                                                   const double* __restrict__ policy,
                                                   bf16* __restrict__ attn) {
    __shared__ float Ks[197 * 69];
    __shared__ float qs[64];
    __shared__ float ps[200];
    __shared__ float red[256];
    const int bh = blockIdx.x, b = bh / H_;
    const int tid = threadIdx.x;
    const float* kbase = k + (size_t)bh * N_ * HD_;
    for (int idx = tid; idx < N_ * HD_; idx += 256) Ks[(idx >> 6) * 69 + (idx & 63)] = kbase[idx];
    for (int j = tid; j < N_; j += 256) ps[j] = (float)policy[b * N_ + j];
    __syncthreads();
    const float* qbase = q + (size_t)bh * N_ * HD_;
    for (int i = 0; i < N_; ++i) {
        if (tid < 64) qs[tid] = qbase[i * HD_ + tid];
        __syncthreads();
        float s = -INFINITY;
        if (tid < N_) {
            float accv = 0.f;
            const float* kr = &Ks[tid * 69];
#pragma unroll
            for (int d = 0; d < 64; ++d) accv += qs[d] * kr[d];
            s = accv * 0.125f;
        }
        float mx = bred_max32(s, red);
        float a = 0.f;
        if (tid < N_) {
            float p = ps[tid];
            float ap = p + (1.f - p) * ((tid == i) ? 1.f : 0.f);
            a = expf(s - mx) * ap;
        }
        float ssum = bred_sum32(a, red);
        if (tid < N_)
            attn[((size_t)bh * N_ + i) * N_ + tid] = f2bf((a + 5.0761421319796954e-9f) / (ssum + 1e-6f));
        __syncthreads();
    }
}

// ---------------- score (fp64) ----------------
__global__ __launch_bounds__(256) void score_kernel(const double* __restrict__ cls,
                                                    const double* __restrict__ vnorm2,
                                                    double* __restrict__ score) {
    __shared__ double red[256];
    const int b = blockIdx.x, t = threadIdx.x;
    double raw = 0.0;
    if (t < N_) {
        double cs = 0.0;
        for (int h = 0; h < H_; ++h) cs += cls[(size_t)(b * H_ + h) * N_ + t];
        raw = cs * sqrt(vnorm2[b * N_ + t]);
    }
    double contrib = (t >= 1 && t < N_) ? raw : 0.0;
    double tot = bred_sum64(contrib, red);
    if (t >= 1 && t < N_) score[(size_t)b * NM1 + (t - 1)] = raw / tot;
}

// ---------------- sampling (fp64 keys) ----------------
DEV void bitonic_fi64(double* key, int* idx) {
    const int tid = threadIdx.x;
    for (int ksz = 2; ksz <= 256; ksz <<= 1)
        for (int jj = ksz >> 1; jj > 0; jj >>= 1) {
            __syncthreads();
            int ixj = tid ^ jj;
            if (ixj > tid) {
                double ka = key[tid], kb = key[ixj];
                int ia = idx[tid], ib = idx[ixj];
                bool up = (tid & ksz) == 0;
                bool agtb = (ka > kb) || (ka == kb && ia > ib);
                if (agtb == up) { key[tid] = kb; key[ixj] = ka; idx[tid] = ib; idx[ixj] = ia; }
            }
        }
    __syncthreads();
}
DEV void bitonic_int(int* a) {
    const int tid = threadIdx.x;
    for (int ksz = 2; ksz <= 256; ksz <<= 1)
        for (int jj = ksz >> 1; jj > 0; jj >>= 1) {
            __syncthreads();
            int ixj = tid ^ jj;
            if (ixj > tid) {
                int va = a[tid], vb = a[ixj];
                bool up = (tid & ksz) == 0;
                if ((va > vb) == up) { a[tid] = vb; a[ixj] = va; }
            }
        }
    __syncthreads();
}

__global__ __launch_bounds__(256) void sample_kernel(const double* __restrict__ score,
                                                     int* __restrict__ srctok) {
    __shared__ double key[256];
    __shared__ int   idx[256];
    __shared__ double ncdf[196];
    __shared__ double red[256];
    __shared__ int   s1[256];
    __shared__ int   s2[256];
    __shared__ double cmm[2];
    const int b = blockIdx.x, tid = threadIdx.x;

    key[tid] = (tid < NM1) ? score[(size_t)b * NM1 + tid] : INFINITY;
    idx[tid] = tid;
    __syncthreads();
    bitonic_fi64(key, idx);            // ascending stable argsort

    if (tid == 0) {                    // sequential cumsum (np order) + min/max
        double c = 0.0, mn = INFINITY, mx = -INFINITY;
        for (int j = 0; j < NM1; ++j) {
            c += key[j]; ncdf[j] = c;
            mn = fmin(mn, c); mx = fmax(mx, c);
        }
        cmm[0] = mn; cmm[1] = mx;
    }
    __syncthreads();
    double cmin = cmm[0], cmax = cmm[1];
    if (tid < NM1) ncdf[tid] = (ncdf[tid] - cmin) / (cmax - cmin);
    __syncthreads();

    double vsm = (tid < NM1) ? (ncdf[tid] + ((ncdf[tid] == 0.0) ? 1e8 : 0.0)) : INFINITY;
    double ys_start = bred_min64(vsm, red);

    int tp = 0x7fffffff;
    if (tid < NM1) {
        double yj = (tid == 195) ? 1.0 : (double)tid * (1.0 / 195.0);   // np.linspace(0,1,196)
        double ys = ys_start + (yj * 195.0 - ys_start * (double)tid) / 195.0;
        double best = fabs(ys - ncdf[0]); int bj = 0;
        for (int j = 1; j < NM1; ++j) {
            double d = fabs(ys - ncdf[j]);
            if (d < best) { best = d; bj = j; }   // first-min (np.argmin)
        }
        tp = bj;
    }
    s1[tid] = tp; __syncthreads();
    bitonic_int(s1);

    int u = 0x7fffffff;
    if (tid < NM1) {
        int sv = s1[tid];
        int nxt = (tid < NM1 - 1) ? s1[tid + 1] : 1;   // shift_left pads with 1
        u = (nxt == sv) ? NM1 : sv;
    }
    __syncthreads();
    s2[tid] = u; __syncthreads();
    bitonic_int(s2);

    if (tid < N_) {
        int st;
        if (tid == 0) st = 0;
        else {
            int uu = s2[tid - 1];
            st = (uu == NM1) ? -1 : (1 + idx[uu]);
        }
        srctok[(size_t)b * N_ + tid] = st;
    }
}

// ---------------- xo = gathered_attn @ v ----------------
__global__ __launch_bounds__(256) void av_kernel(const bf16* __restrict__ attn,
                                                 const float* __restrict__ v,
                                                 const int* __restrict__ srctok,
                                                 float* __restrict__ xo) {
    __shared__ float Vs[197 * 64];
    const int bh = blockIdx.x;
    const int b = bh / H_, h = bh - b * H_;
    const int tid = threadIdx.x;
    const float* vbase = v + (size_t)bh * N_ * HD_;
    for (int i = tid; i < N_ * HD_; i += 256) Vs[i] = vbase[i];
    __syncthreads();
    const int w = tid >> 6, lane = tid & 63;
    for (int r = w; r < N_; r += 4) {
        int st = srctok[(size_t)b * N_ + r];
        float accv = 0.f;
        if (st >= 0) {
            const bf16* ar = attn + ((size_t)bh * N_ + st) * N_;
#pragma unroll 4
            for (int m = 0; m < N_; ++m) accv += bf2f(ar[m]) * Vs[m * 64 + lane];
        }
        xo[((size_t)(b * N_) + r) * C_ + h * 64 + lane] = accv;
    }
}

// ---------------- launch ----------------
extern "C" void kernel_launch(void* const* d_in, const int* in_sizes, int n_in,
                              void* d_out, int out_size, void* d_ws, size_t ws_size,
                              hipStream_t stream) {
    // workspace layout (bytes); total ~218.2 MB (well under r2's proven 243.6 MB)
    char* ws = (char*)d_ws;
    int*    flag    = (int*)   (ws + 0);            //        256
    double* w64     = (double*)(ws + 256);          // 14,155,776
    float*  wproj32 = (float*) (ws + 14156032);     //  2,359,296
    float*  wfc1_32 = (float*) (ws + 16515328);     //  9,437,184
    float*  wfc2_32 = (float*) (ws + 25952512);     //  9,437,184
    double* pol64   = (double*)(ws + 35389696);     //    100,864
    double* g1_64   = (double*)(ws + 35490560);     //      6,144
    double* b1_64   = (double*)(ws + 35496704);     //      6,144
    float*  g2_32   = (float*) (ws + 35502848);     //      3,072
    float*  b2_32   = (float*) (ws + 35505920);     //      3,072
    float*  bproj32 = (float*) (ws + 35508992);     //      3,072
    float*  bfc1_32 = (float*) (ws + 35512064);     //     12,288
    float*  bfc2_32 = (float*) (ws + 35524352);     //      3,072
    double* q0_64   = (double*)(ws + 35527424);     //    393,216
    double* wq0_64  = (double*)(ws + 35920640);     //  4,718,592
    double* vnorm2  = (double*)(ws + 40639232);     //    100,864
    double* cls64   = (double*)(ws + 40740096);     //  1,210,368
    double* score64 = (double*)(ws + 41950464);     //    100,352
    int*    srctok  = (int*)   (ws + 42050816);     //     50,432
    double* xn64    = (double*)(ws + 42101248);     // 77,463,552 [-> xo32 -> act]
    float*  q32     = (float*) (ws + 119564800);    // 12,910,592
    float*  k32     = (float*) (ws + 132475392);    // 12,910,592
    float*  v32     = (float*) (ws + 145385984);    // 12,910,592 [q/k/v -> h1_32]
    bf16*   attn    = (bf16*)  (ws + 158296576);    // 59,610,624 [-> x2_32]
    float*  xo32    = (float*) (ws + 42101248);     // overlays xn64 (dead after cls)
    bf16*   act     = (bf16*)  (ws + 42101248);     // overlays xn64/xo32 (dead after proj)
    float*  h1_32   = (float*) (ws + 119564800);    // overlays q/k/v32 (dead after attn/av)
    float*  x2_32   = (float*) (ws + 158296576);    // overlays attn (dead after av)

    const dim3 blk(256);

    // 0) dtype detect, then flag-dispatched conversions + vnorm2 zero-init
    detect_kernel<<<1, blk, 0, stream>>>((const unsigned short*)d_in[2], flag);
    cvt64_kernel<<<1024, blk, 0, stream>>>(d_in[2],  w64,     C_ * C3_, flag);
    cvt32_kernel<<<576,  blk, 0, stream>>>(d_in[3],  wproj32, C_ * C_,  flag);
    cvt32_kernel<<<3,    blk, 0, stream>>>(d_in[4],  bproj32, C_,       flag);
    cvt64_kernel<<<3,    blk, 0, stream>>>(d_in[5],  g1_64,   C_,       flag);
    cvt64_kernel<<<3,    blk, 0, stream>>>(d_in[6],  b1_64,   C_,       flag);
    cvt32_kernel<<<3,    blk, 0, stream>>>(d_in[7],  g2_32,   C_,       flag);
    cvt32_kernel<<<3,    blk, 0, stream>>>(d_in[8],  b2_32,   C_,       flag);
    cvt32_kernel<<<1024, blk, 0, stream>>>(d_in[9],  wfc1_32, C_ * C4_, flag);
    cvt32_kernel<<<12,   blk, 0, stream>>>(d_in[10], bfc1_32, C4_,      flag);
    cvt32_kernel<<<1024, blk, 0, stream>>>(d_in[11], wfc2_32, C4_ * C_, flag);
    cvt32_kernel<<<3,    blk, 0, stream>>>(d_in[12], bfc2_32, C_,       flag);
    cvt64_kernel<<<50,   blk, 0, stream>>>(d_in[1],  pol64,   M_,       flag);
    zero64_kernel<<<50,  blk, 0, stream>>>(vnorm2, M_);

    // 1) LN1 fp64 (reads raw x via flag)
    ln64_kernel<<<M_, blk, 0, stream>>>(d_in[0], g1_64, b1_64, xn64, flag);

    // 2) fp64 score-path precursors: q0, wq0
    q0_kernel<<<B_, blk, 0, stream>>>(xn64, w64, pol64, q0_64);
    wq0_kernel<<<B_, blk, 0, stream>>>(w64, q0_64, wq0_64);

    // 3) q,k fp32 GEMM (continuous path)
    gemm_qk32<<<dim3(2 * C_ / 128, (M_ + 127) / 128), blk, 0, stream>>>(xn64, w64, pol64, q32, k32);

    // 4) v fp64 GEMM (score-critical norm) -> v32 + vnorm2
    gemm64_v<<<dim3(C_ / 64, M_ / 64), blk, 0, stream>>>(xn64, w64, pol64, v32, vnorm2);

    // 5) cls row softmax fp64 (xn64 last use)
    cls_kernel<<<BH_, blk, 0, stream>>>(xn64, wq0_64, pol64, cls64);

    // 6) attention probs fp32 -> bf16
    attn_kernel<<<BH_, blk, 0, stream>>>(q32, k32, pol64, attn);

    // 7) score + sampling (fp64)
    score_kernel<<<B_, blk, 0, stream>>>(cls64, vnorm2, score64);
    sample_kernel<<<B_, blk, 0, stream>>>(score64, srctok);

    // 8) xo = gathered attn @ v  (xo into xn64 slot)
    av_kernel<<<BH_, blk, 0, stream>>>(attn, v32, srctok, xo32);

    // 9) proj -> x2 (attn slot)
    { Epi e = {}; e.bias = bproj32; e.srctok = srctok; e.xin = d_in[0]; e.x2out = x2_32; e.flagp = flag;
      gemm_k<1, float><<<dim3(C_ / 128, (M_ + 127) / 128), blk, 0, stream>>>(xo32, wproj32, M_, C_, C_, e); }

    // 10) LN2 fp32 -> h1 (q/k/v slot)
    ln32_kernel<<<M_, blk, 0, stream>>>(x2_32, g2_32, b2_32, h1_32);

    // 11) fc1 + GELU -> act bf16 (xn64 slot)
    { Epi e = {}; e.bias = bfc1_32; e.act = act;
      gemm_k<2, float><<<dim3(C4_ / 128, (M_ + 127) / 128), blk, 0, stream>>>(h1_32, wfc1_32, M_, C4_, C_, e); }

    // 12) fc2 + residual + pol -> out (dtype per flag)
    { Epi e = {}; e.bias = bfc2_32; e.srctok = srctok; e.x2in = x2_32; e.dout = d_out; e.flagp = flag;
      gemm_k<3, bf16><<<dim3(C_ / 128, (M_ + 127) / 128), blk, 0, stream>>>(act, wfc2_32, M_, C_, C4_, e); }
}

// Round 5
// 4645.435 us; speedup vs baseline: 1.1190x; 1.1190x over previous
//
#include <hip/hip_runtime.h>
#include <hip/hip_bf16.h>
#include <cmath>

typedef __hip_bfloat16 bf16;
#define DEV static __device__ __forceinline__

DEV float bf2f(bf16 x) { return __bfloat162float(x); }
DEV bf16  f2bf(float x) { return __float2bfloat16(x); }
DEV float bfraw2f(unsigned int h) { return __uint_as_float(h << 16); }

constexpr int B_  = 64, N_ = 197, C_ = 768, H_ = 12, HD_ = 64;
constexpr int C3_ = 3 * C_;      // 2304
constexpr int C4_ = 4 * C_;      // 3072
constexpr int M_  = B_ * N_;     // 12608
constexpr int BH_ = B_ * H_;     // 768
constexpr int NM1 = N_ - 1;      // 196

// ---------------- dtype detection ----------------
__global__ __launch_bounds__(256) void detect_kernel(const unsigned short* __restrict__ w,
                                                     int* __restrict__ flag) {
    __shared__ int cnt;
    if (threadIdx.x == 0) cnt = 0;
    __syncthreads();
    int c = 0;
#pragma unroll
    for (int k = 0; k < 8; ++k) {
        unsigned short u = w[threadIdx.x * 8 + k];
        int e = (u >> 7) & 0xFF;
        if (e >= 143) ++c;
    }
    atomicAdd(&cnt, c);
    __syncthreads();
    if (threadIdx.x == 0) *flag = (cnt >= 8) ? 1 : 0;   // 1 = fp32 inputs
}

DEV float load_in(const void* p, size_t i, bool f32) {
    return f32 ? ((const float*)p)[i] : bf2f(((const bf16*)p)[i]);
}

// ---------------- converters (flag-dispatched) ----------------
__global__ __launch_bounds__(256) void cvt32_kernel(const void* __restrict__ s, float* __restrict__ d,
                                                    int n, const int* __restrict__ flag) {
    const bool f32 = (*flag != 0);
    int i = blockIdx.x * 256 + threadIdx.x, st = gridDim.x * 256;
    for (; i < n; i += st) d[i] = load_in(s, i, f32);
}
__global__ __launch_bounds__(256) void cvt64_kernel(const void* __restrict__ s, double* __restrict__ d,
                                                    int n, const int* __restrict__ flag) {
    const bool f32 = (*flag != 0);
    int i = blockIdx.x * 256 + threadIdx.x, st = gridDim.x * 256;
    for (; i < n; i += st) d[i] = (double)load_in(s, i, f32);
}
__global__ __launch_bounds__(256) void zero64_kernel(double* __restrict__ d, int n) {
    int i = blockIdx.x * 256 + threadIdx.x, st = gridDim.x * 256;
    for (; i < n; i += st) d[i] = 0.0;
}

// ---------------- block reductions ----------------
DEV double bred_sum64(double v, double* red) {
    int t = threadIdx.x; red[t] = v; __syncthreads();
    for (int s = 128; s > 0; s >>= 1) { if (t < s) red[t] += red[t + s]; __syncthreads(); }
    double r = red[0]; __syncthreads(); return r;
}
DEV double bred_min64(double v, double* red) {
    int t = threadIdx.x; red[t] = v; __syncthreads();
    for (int s = 128; s > 0; s >>= 1) { if (t < s) red[t] = fmin(red[t], red[t + s]); __syncthreads(); }
    double r = red[0]; __syncthreads(); return r;
}
DEV float bred_sum32(float v, float* red) {
    int t = threadIdx.x; red[t] = v; __syncthreads();
    for (int s = 128; s > 0; s >>= 1) { if (t < s) red[t] += red[t + s]; __syncthreads(); }
    float r = red[0]; __syncthreads(); return r;
}

// ---------------- LN1 fp64: raw x -> xn64 (+ fp32 copy for qk GEMM) ----------------
__global__ __launch_bounds__(256) void ln64_kernel(const void* __restrict__ in,
                                                   const double* __restrict__ g,
                                                   const double* __restrict__ bb,
                                                   double* __restrict__ out,
                                                   float* __restrict__ out32,
                                                   const int* __restrict__ flag) {
    __shared__ double red[256];
    const bool f32 = (*flag != 0);
    const int tid = threadIdx.x;
    const size_t row = blockIdx.x;
    double x0 = (double)load_in(in, row * C_ + tid, f32);
    double x1 = (double)load_in(in, row * C_ + tid + 256, f32);
    double x2 = (double)load_in(in, row * C_ + tid + 512, f32);
    double m = bred_sum64(x0 + x1 + x2, red) / 768.0;
    double d0 = x0 - m, d1 = x1 - m, d2 = x2 - m;
    double var = bred_sum64(d0 * d0 + d1 * d1 + d2 * d2, red) / 768.0;
    double istd = 1.0 / sqrt(var + 1e-5);
    double* op = out + row * C_;
    double v0 = (d0 * istd) * g[tid]     + bb[tid];
    double v1 = (d1 * istd) * g[tid+256] + bb[tid+256];
    double v2 = (d2 * istd) * g[tid+512] + bb[tid+512];
    op[tid] = v0; op[tid+256] = v1; op[tid+512] = v2;
    float* op32 = out32 + row * C_;
    op32[tid] = (float)v0; op32[tid+256] = (float)v1; op32[tid+512] = (float)v2;
}

// ---------------- LN2 fp32 ----------------
__global__ __launch_bounds__(256) void ln32_kernel(const float* __restrict__ in,
                                                   const float* __restrict__ g,
                                                   const float* __restrict__ bb,
                                                   float* __restrict__ out) {
    __shared__ float red[256];
    const int tid = threadIdx.x;
    const size_t row = blockIdx.x;
    const float* xp = in + row * C_;
    float x0 = xp[tid], x1 = xp[tid + 256], x2 = xp[tid + 512];
    float m = bred_sum32(x0 + x1 + x2, red) * (1.0f / 768.0f);
    float d0 = x0 - m, d1 = x1 - m, d2 = x2 - m;
    float var = bred_sum32(d0 * d0 + d1 * d1 + d2 * d2, red) * (1.0f / 768.0f);
    float istd = 1.0f / sqrtf(var + 1e-5f);
    float* op = out + row * C_;
    op[tid]     = d0 * istd * g[tid]     + bb[tid];
    op[tid+256] = d1 * istd * g[tid+256] + bb[tid+256];
    op[tid+512] = d2 * istd * g[tid+512] + bb[tid+512];
}

// ---------------- q0: fp64 q of token 0, policy folded ----------------
__global__ __launch_bounds__(256) void q0_kernel(const double* __restrict__ xn64,
                                                 const double* __restrict__ w64,
                                                 const double* __restrict__ pol,
                                                 double* __restrict__ q0) {
    const int b = blockIdx.x, tid = threadIdx.x;
    const double* xr = xn64 + (size_t)(b * N_) * C_;
    double p0 = pol[b * N_];
    for (int j = tid; j < C_; j += 256) {
        double acc = 0.0;
        for (int c = 0; c < C_; ++c) acc += xr[c] * w64[(size_t)c * C3_ + j];
        q0[(size_t)b * C_ + j] = acc * p0;
    }
}

// ---------------- wq0[b,h,c] = sum_d Wk[c, 768+h*64+d] * q0[b,h,d] ----------------
__global__ __launch_bounds__(256) void wq0_kernel(const double* __restrict__ w64,
                                                  const double* __restrict__ q0,
                                                  double* __restrict__ wq0) {
    const int b = blockIdx.x, tid = threadIdx.x;
    for (int idx = tid; idx < H_ * C_; idx += 256) {
        int h = idx / C_, c = idx - h * C_;
        const double* wr = w64 + (size_t)c * C3_ + C_ + h * HD_;
        const double* qr = q0 + (size_t)b * C_ + h * HD_;
        double acc = 0.0;
#pragma unroll 8
        for (int d = 0; d < HD_; ++d) acc += wr[d] * qr[d];
        wq0[((size_t)b * H_ + h) * C_ + c] = acc;
    }
}

// ---------------- cls rows: fp64 softmax of (xn64 . wq0)*pol*0.125, block per b ----------------
__global__ __launch_bounds__(256) void cls_kernel(const double* __restrict__ xn64,
                                                  const double* __restrict__ wq0,
                                                  const double* __restrict__ pol,
                                                  double* __restrict__ cls) {
    __shared__ double wsh[6][768];
    __shared__ double sarr[6][200];
    const int b = blockIdx.x;
    const int tid = threadIdx.x, w = tid >> 6, lane = tid & 63;
    for (int ph = 0; ph < 2; ++ph) {
        for (int idx = tid; idx < 6 * 768; idx += 256) {
            int h = idx / 768, c = idx - h * 768;
            wsh[h][c] = wq0[((size_t)b * H_ + ph * 6 + h) * C_ + c];
        }
        __syncthreads();
        for (int t = w; t < N_; t += 4) {
            const double* xr = xn64 + (size_t)(b * N_ + t) * C_;
            double xreg[12];
#pragma unroll
            for (int ch = 0; ch < 12; ++ch) xreg[ch] = xr[ch * 64 + lane];
            double pm = pol[b * N_ + t] * 0.125;
            for (int h = 0; h < 6; ++h) {
                double acc = 0.0;
#pragma unroll
                for (int ch = 0; ch < 12; ++ch) acc += xreg[ch] * wsh[h][ch * 64 + lane];
                for (int off = 32; off > 0; off >>= 1) acc += __shfl_down(acc, off, 64);
                if (lane == 0) sarr[h][t] = acc * pm;
            }
        }
        __syncthreads();
        for (int hh = w; hh < 6; hh += 4) {
            const int j0 = lane, j1 = lane + 64, j2 = lane + 128, j3 = lane + 192;
            const bool h3 = (lane < 5);
            double s0 = sarr[hh][j0], s1 = sarr[hh][j1], s2 = sarr[hh][j2];
            double s3 = h3 ? sarr[hh][j3] : -INFINITY;
            double m = fmax(fmax(s0, s2), fmax(s1, s3));
            for (int off = 32; off > 0; off >>= 1) m = fmax(m, __shfl_down(m, off, 64));
            double mx = __shfl(m, 0, 64);
            double p0 = pol[b * N_ + j0], p1 = pol[b * N_ + j1], p2 = pol[b * N_ + j2];
            double e0 = exp(s0 - mx) * (p0 + (1.0 - p0));          // j0==0 only when lane==0
            if (j0 != 0) e0 = exp(s0 - mx) * p0;
            double e1 = exp(s1 - mx) * p1;
            double e2 = exp(s2 - mx) * p2;
            double e3 = 0.0;
            if (h3) { double p3 = pol[b * N_ + j3]; e3 = exp(s3 - mx) * p3; }
            double su = (e0 + e2) + (e1 + e3);
            for (int off = 32; off > 0; off >>= 1) su += __shfl_down(su, off, 64);
            double ssum = __shfl(su, 0, 64);
            double* crow = cls + ((size_t)b * H_ + ph * 6 + hh) * N_;
            crow[j0] = (e0 + 1e-6 / 197.0) / (ssum + 1e-6);
            crow[j1] = (e1 + 1e-6 / 197.0) / (ssum + 1e-6);
            crow[j2] = (e2 + 1e-6 / 197.0) / (ssum + 1e-6);
            if (h3) crow[j3] = (e3 + 1e-6 / 197.0) / (ssum + 1e-6);
        }
        __syncthreads();
    }
}

// ---------------- fp64 GEMM for V: 64x64 tile, 4x4 micro (decision path — untouched) ----------------
__global__ __launch_bounds__(256) void gemm64_v(const double* __restrict__ A,
                                                const double* __restrict__ W,
                                                const double* __restrict__ pol,
                                                float* __restrict__ v32,
                                                double* __restrict__ vnorm2) {
    __shared__ double As[16][65];
    __shared__ double Bs[16][68];
    const int tid = threadIdx.x;
    const int tx = tid & 15, ty = tid >> 4;
    const int bx = blockIdx.x, by = blockIdx.y;
    const int arow = tid & 63, ak = (tid >> 6) * 4;
    const int brow = tid >> 4, bcol = (tid & 15) * 4;

    double acc[4][4];
#pragma unroll
    for (int i = 0; i < 4; ++i)
#pragma unroll
        for (int j = 0; j < 4; ++j) acc[i][j] = 0.0;

    const int gr = by * 64 + arow;
    for (int k0 = 0; k0 < C_; k0 += 16) {
        const double* ap = A + (size_t)gr * C_ + k0 + ak;
        double a0 = ap[0], a1 = ap[1], a2 = ap[2], a3 = ap[3];
        const double* bp = W + (size_t)(k0 + brow) * C3_ + 2 * C_ + bx * 64 + bcol;
        double b0 = bp[0], b1 = bp[1], b2 = bp[2], b3 = bp[3];
        __syncthreads();
        As[ak + 0][arow] = a0; As[ak + 1][arow] = a1; As[ak + 2][arow] = a2; As[ak + 3][arow] = a3;
        Bs[brow][bcol + 0] = b0; Bs[brow][bcol + 1] = b1; Bs[brow][bcol + 2] = b2; Bs[brow][bcol + 3] = b3;
        __syncthreads();
#pragma unroll
        for (int kk = 0; kk < 16; ++kk) {
            double aa[4], bb[4];
#pragma unroll
            for (int i = 0; i < 4; ++i) aa[i] = As[kk][ty * 4 + i];
#pragma unroll
            for (int j = 0; j < 4; ++j) bb[j] = Bs[kk][tx * 4 + j];
#pragma unroll
            for (int i = 0; i < 4; ++i)
#pragma unroll
                for (int j = 0; j < 4; ++j) acc[i][j] += aa[i] * bb[j];
        }
    }
    const int col0 = bx * 64 + tx * 4;
    const int h = col0 >> 6, d0 = col0 & 63;
#pragma unroll
    for (int i = 0; i < 4; ++i) {
        int row = by * 64 + ty * 4 + i;
        int b = row / N_, nn = row - b * N_;
        double p = pol[row];
        double s2 = 0.0;
        float* dst = v32 + (((size_t)(b * H_ + h)) * N_ + nn) * HD_ + d0;
#pragma unroll
        for (int j = 0; j < 4; ++j) {
            double vv = acc[i][j] * p;
            dst[j] = (float)vv;
            s2 += vv * vv;
        }
        atomicAdd(&vnorm2[row], s2);
    }
}

// ---------------- fp32 GEMM, 128x128x16, 8x8 microtile (split 4+4 cols, bank-conflict-free) ----------------
struct Epi {
    const float* bias;
    const int* srctok;
    const void* xin;
    float* x2out;
    bf16* act;
    const float* x2in;
    void* dout;
    const int* flagp;
    float* qq; float* kk;
    const double* pol;
};

// MODE: 0 = qk scatter (*policy), 1 = proj -> x2 (+sel_x, *pol), 2 = fc1 gelu -> act(bf16), 3 = fc2 -> out
template <int MODE, typename TA>
__global__ __launch_bounds__(256) void gemm_k(const TA* __restrict__ A,
                                              const float* __restrict__ Bw,
                                              int M, int Nn, int K, Epi ep) {
    __shared__ float As[16][128];
    __shared__ float Bs[16][132];
    const int tid = threadIdx.x;
    const int tx = tid & 15, ty = tid >> 4;
    const int bx = blockIdx.x, by = blockIdx.y;
    const int arow = tid >> 1, ak0 = (tid & 1) * 8;
    const int brow = tid >> 4, bcol = (tid & 15) * 8;

    float acc[8][8];
#pragma unroll
    for (int i = 0; i < 8; ++i)
#pragma unroll
        for (int j = 0; j < 8; ++j) acc[i][j] = 0.f;

    const int gr = by * 128 + arow;
    for (int k0 = 0; k0 < K; k0 += 16) {
        float av[8];
        if (gr < M) {
            const TA* ap = A + (size_t)gr * K + k0 + ak0;
            if constexpr (sizeof(TA) == 4) {
                const float4* p4 = (const float4*)ap;
                float4 t0 = p4[0], t1 = p4[1];
                av[0]=t0.x; av[1]=t0.y; av[2]=t0.z; av[3]=t0.w;
                av[4]=t1.x; av[5]=t1.y; av[6]=t1.z; av[7]=t1.w;
            } else {
                uint4 u = *(const uint4*)ap;
                av[0]=bfraw2f(u.x & 0xffffu); av[1]=bfraw2f(u.x >> 16);
                av[2]=bfraw2f(u.y & 0xffffu); av[3]=bfraw2f(u.y >> 16);
                av[4]=bfraw2f(u.z & 0xffffu); av[5]=bfraw2f(u.z >> 16);
                av[6]=bfraw2f(u.w & 0xffffu); av[7]=bfraw2f(u.w >> 16);
            }
        } else {
#pragma unroll
            for (int j = 0; j < 8; ++j) av[j] = 0.f;
        }
        const float* bp = Bw + (size_t)(k0 + brow) * Nn + bx * 128 + bcol;
        float4 u0 = ((const float4*)bp)[0];
        float4 u1 = ((const float4*)bp)[1];
        __syncthreads();
#pragma unroll
        for (int j = 0; j < 8; ++j) As[ak0 + j][arow] = av[j];
        Bs[brow][bcol+0]=u0.x; Bs[brow][bcol+1]=u0.y; Bs[brow][bcol+2]=u0.z; Bs[brow][bcol+3]=u0.w;
        Bs[brow][bcol+4]=u1.x; Bs[brow][bcol+5]=u1.y; Bs[brow][bcol+6]=u1.z; Bs[brow][bcol+7]=u1.w;
        __syncthreads();

#pragma unroll
        for (int kk = 0; kk < 16; ++kk) {
            float4 a0 = *(const float4*)&As[kk][ty * 8];
            float4 a1 = *(const float4*)&As[kk][ty * 8 + 4];
            float4 b0 = *(const float4*)&Bs[kk][tx * 4];        // cols tx*4..+3
            float4 b1 = *(const float4*)&Bs[kk][64 + tx * 4];   // cols 64+tx*4..+3
            float aa[8] = {a0.x,a0.y,a0.z,a0.w,a1.x,a1.y,a1.z,a1.w};
            float bb[8] = {b0.x,b0.y,b0.z,b0.w,b1.x,b1.y,b1.z,b1.w};
#pragma unroll
            for (int i = 0; i < 8; ++i)
#pragma unroll
                for (int j = 0; j < 8; ++j) acc[i][j] += aa[i] * bb[j];
        }
    }
    const int row0 = by * 128 + ty * 8;
    const int cb[2] = { bx * 128 + tx * 4, bx * 128 + 64 + tx * 4 };

    if constexpr (MODE == 0) {
#pragma unroll
        for (int g = 0; g < 2; ++g) {
            int col = cb[g];
            int comp = col >= C_ ? 1 : 0;
            int rem = col - comp * C_;
            int h = rem >> 6, d0 = rem & 63;
            float* dstbase = comp ? ep.kk : ep.qq;
#pragma unroll
            for (int i = 0; i < 8; ++i) {
                int row = row0 + i; if (row >= M) break;
                int b = row / N_, nn = row - b * N_;
                float pv = (float)ep.pol[row];
                float* dst = dstbase + (((size_t)(b * H_ + h)) * N_ + nn) * HD_ + d0;
#pragma unroll
                for (int jj = 0; jj < 4; ++jj) dst[jj] = acc[i][g * 4 + jj] * pv;
            }
        }
    } else if constexpr (MODE == 1) {
        const bool f32 = (*ep.flagp != 0);
#pragma unroll
        for (int i = 0; i < 8; ++i) {
            int row = row0 + i; if (row >= M) break;
            int st = ep.srctok[row];
            float polv = (st >= 0) ? 1.f : 0.f;
            int b = row / N_;
            size_t xrow = ((size_t)(b * N_ + (st < 0 ? 0 : st))) * C_;
#pragma unroll
            for (int g = 0; g < 2; ++g) {
                int col = cb[g];
                float* o = ep.x2out + (size_t)row * C_ + col;
#pragma unroll
                for (int jj = 0; jj < 4; ++jj) {
                    float selx = (st >= 0) ? load_in(ep.xin, xrow + col + jj, f32) : 0.f;
                    o[jj] = selx + (acc[i][g * 4 + jj] + ep.bias[col + jj]) * polv;
                }
            }
        }
    } else if constexpr (MODE == 2) {
#pragma unroll
        for (int i = 0; i < 8; ++i) {
            int row = row0 + i; if (row >= M) break;
#pragma unroll
            for (int g = 0; g < 2; ++g) {
                int col = cb[g];
                bf16* o = ep.act + (size_t)row * C4_ + col;
#pragma unroll
                for (int jj = 0; jj < 4; ++jj) {
                    float z = acc[i][g * 4 + jj] + ep.bias[col + jj];
                    float gl = 0.5f * z * (1.0f + erff(z * 0.70710678118654752f));
                    o[jj] = f2bf(gl);
                }
            }
        }
    } else {
        const bool f32out = (*ep.flagp != 0);
#pragma unroll
        for (int i = 0; i < 8; ++i) {
            int row = row0 + i; if (row >= M) break;
            int st = ep.srctok[row];
            float polv = (st >= 0) ? 1.f : 0.f;
#pragma unroll
            for (int g = 0; g < 2; ++g) {
                int col = cb[g];
                const float* x2r = ep.x2in + (size_t)row * C_ + col;
                size_t obase = (size_t)row * C_ + col;
#pragma unroll
                for (int jj = 0; jj < 4; ++jj) {
                    float hv = acc[i][g * 4 + jj] + ep.bias[col + jj];
                    float val = (x2r[jj] + hv) * polv;
                    if (f32out) ((float*)ep.dout)[obase + jj] = val;
                    else        ((bf16*)ep.dout)[obase + jj] = f2bf(val);
                }
            }
        }
    }
}

// ---------------- attention probs: wave-per-row, bit-identical 256-slot reduction tree ----------------
__global__ __launch_bounds__(256) void attn_kernel(const float* __restrict__ q,
                                                   const float* __restrict__ k,
                                                   const double* __restrict__ policy,
                                                   bf16* __restrict__ attn) {
    __shared__ float Ks[197 * 69];
    __shared__ float ps[256];
    const int bh = blockIdx.x, b = bh / H_;
    const int tid = threadIdx.x;
    const float* kbase = k + (size_t)bh * N_ * HD_;
    for (int idx = tid; idx < N_ * HD_; idx += 256) Ks[(idx >> 6) * 69 + (idx & 63)] = kbase[idx];
    for (int j = tid; j < 256; j += 256) ps[j] = (j < N_) ? (float)policy[b * N_ + j] : 0.f;
    __syncthreads();
    const int w = tid >> 6, lane = tid & 63;
    const int j0 = lane, j1 = lane + 64, j2 = lane + 128, j3 = lane + 192;
    const bool h3 = (lane < 5);
    const float* k0p = &Ks[j0 * 69];
    const float* k1p = &Ks[j1 * 69];
    const float* k2p = &Ks[j2 * 69];
    const float* k3p = h3 ? &Ks[j3 * 69] : &Ks[j0 * 69];
    const float p0 = ps[j0], p1 = ps[j1], p2 = ps[j2], p3 = h3 ? ps[j3] : 0.f;
    const float* qbase = q + (size_t)bh * N_ * HD_;
    for (int i = w; i < N_; i += 4) {
        const float* qr = qbase + i * HD_;
        float a0 = 0.f, a1 = 0.f, a2 = 0.f, a3 = 0.f;
#pragma unroll 8
        for (int d = 0; d < 64; ++d) {
            float qd = qr[d];
            a0 += qd * k0p[d]; a1 += qd * k1p[d]; a2 += qd * k2p[d]; a3 += qd * k3p[d];
        }
        float s0 = a0 * 0.125f, s1 = a1 * 0.125f, s2 = a2 * 0.125f;
        float s3 = h3 ? a3 * 0.125f : -INFINITY;
        // max over the same 256-slot tree: step128/64 local, then 6 shuffle steps
        float m = fmaxf(fmaxf(s0, s2), fmaxf(s1, s3));
        for (int off = 32; off > 0; off >>= 1) m = fmaxf(m, __shfl_down(m, off, 64));
        float mx = __shfl(m, 0, 64);
        float e0 = expf(s0 - mx) * (p0 + (1.f - p0) * ((j0 == i) ? 1.f : 0.f));
        float e1 = expf(s1 - mx) * (p1 + (1.f - p1) * ((j1 == i) ? 1.f : 0.f));
        float e2 = expf(s2 - mx) * (p2 + (1.f - p2) * ((j2 == i) ? 1.f : 0.f));
        float e3 = h3 ? expf(s3 - mx) * (p3 + (1.f - p3) * ((j3 == i) ? 1.f : 0.f)) : 0.f;
        // sum over the same 256-slot tree (identical operand order)
        float su = (e0 + e2) + (e1 + e3);
        for (int off = 32; off > 0; off >>= 1) su += __shfl_down(su, off, 64);
        float ssum = __shfl(su, 0, 64);
        bf16* orow = attn + ((size_t)bh * N_ + i) * N_;
        orow[j0] = f2bf((e0 + 5.0761421319796954e-9f) / (ssum + 1e-6f));
        orow[j1] = f2bf((e1 + 5.0761421319796954e-9f) / (ssum + 1e-6f));
        orow[j2] = f2bf((e2 + 5.0761421319796954e-9f) / (ssum + 1e-6f));
        if (h3) orow[j3] = f2bf((e3 + 5.0761421319796954e-9f) / (ssum + 1e-6f));
    }
}

// ---------------- score (fp64) ----------------
__global__ __launch_bounds__(256) void score_kernel(const double* __restrict__ cls,
                                                    const double* __restrict__ vnorm2,
                                                    double* __restrict__ score) {
    __shared__ double red[256];
    const int b = blockIdx.x, t = threadIdx.x;
    double raw = 0.0;
    if (t < N_) {
        double cs = 0.0;
        for (int h = 0; h < H_; ++h) cs += cls[(size_t)(b * H_ + h) * N_ + t];
        raw = cs * sqrt(vnorm2[b * N_ + t]);
    }
    double contrib = (t >= 1 && t < N_) ? raw : 0.0;
    double tot = bred_sum64(contrib, red);
    if (t >= 1 && t < N_) score[(size_t)b * NM1 + (t - 1)] = raw / tot;
}

// ---------------- sampling (fp64 keys) ----------------
DEV void bitonic_fi64(double* key, int* idx) {
    const int tid = threadIdx.x;
    for (int ksz = 2; ksz <= 256; ksz <<= 1)
        for (int jj = ksz >> 1; jj > 0; jj >>= 1) {
            __syncthreads();
            int ixj = tid ^ jj;
            if (ixj > tid) {
                double ka = key[tid], kb = key[ixj];
                int ia = idx[tid], ib = idx[ixj];
                bool up = (tid & ksz) == 0;
                bool agtb = (ka > kb) || (ka == kb && ia > ib);
                if (agtb == up) { key[tid] = kb; key[ixj] = ka; idx[tid] = ib; idx[ixj] = ia; }
            }
        }
    __syncthreads();
}
DEV void bitonic_int(int* a) {
    const int tid = threadIdx.x;
    for (int ksz = 2; ksz <= 256; ksz <<= 1)
        for (int jj = ksz >> 1; jj > 0; jj >>= 1) {
            __syncthreads();
            int ixj = tid ^ jj;
            if (ixj > tid) {
                int va = a[tid], vb = a[ixj];
                bool up = (tid & ksz) == 0;
                if ((va > vb) == up) { a[tid] = vb; a[ixj] = va; }
            }
        }
    __syncthreads();
}

__global__ __launch_bounds__(256) void sample_kernel(const double* __restrict__ score,
                                                     int* __restrict__ srctok) {
    __shared__ double key[256];
    __shared__ int   idx[256];
    __shared__ double ncdf[196];
    __shared__ double red[256];
    __shared__ int   s1[256];
    __shared__ int   s2[256];
    __shared__ double cmm[2];
    const int b = blockIdx.x, tid = threadIdx.x;

    key[tid] = (tid < NM1) ? score[(size_t)b * NM1 + tid] : INFINITY;
    idx[tid] = tid;
    __syncthreads();
    bitonic_fi64(key, idx);

    if (tid == 0) {
        double c = 0.0, mn = INFINITY, mx = -INFINITY;
        for (int j = 0; j < NM1; ++j) {
            c += key[j]; ncdf[j] = c;
            mn = fmin(mn, c); mx = fmax(mx, c);
        }
        cmm[0] = mn; cmm[1] = mx;
    }
    __syncthreads();
    double cmin = cmm[0], cmax = cmm[1];
    if (tid < NM1) ncdf[tid] = (ncdf[tid] - cmin) / (cmax - cmin);
    __syncthreads();

    double vsm = (tid < NM1) ? (ncdf[tid] + ((ncdf[tid] == 0.0) ? 1e8 : 0.0)) : INFINITY;
    double ys_start = bred_min64(vsm, red);

    int tp = 0x7fffffff;
    if (tid < NM1) {
        double yj = (tid == 195) ? 1.0 : (double)tid * (1.0 / 195.0);
        double ys = ys_start + (yj * 195.0 - ys_start * (double)tid) / 195.0;
        double best = fabs(ys - ncdf[0]); int bj = 0;
        for (int j = 1; j < NM1; ++j) {
            double d = fabs(ys - ncdf[j]);
            if (d < best) { best = d; bj = j; }
        }
        tp = bj;
    }
    s1[tid] = tp; __syncthreads();
    bitonic_int(s1);

    int u = 0x7fffffff;
    if (tid < NM1) {
        int sv = s1[tid];
        int nxt = (tid < NM1 - 1) ? s1[tid + 1] : 1;
        u = (nxt == sv) ? NM1 : sv;
    }
    __syncthreads();
    s2[tid] = u; __syncthreads();
    bitonic_int(s2);

    if (tid < N_) {
        int st;
        if (tid == 0) st = 0;
        else {
            int uu = s2[tid - 1];
            st = (uu == NM1) ? -1 : (1 + idx[uu]);
        }
        srctok[(size_t)b * N_ + tid] = st;
    }
}

// ---------------- xo = gathered_attn @ v ----------------
__global__ __launch_bounds__(256) void av_kernel(const bf16* __restrict__ attn,
                                                 const float* __restrict__ v,
                                                 const int* __restrict__ srctok,
                                                 float* __restrict__ xo) {
    __shared__ float Vs[197 * 64];
    const int bh = blockIdx.x;
    const int b = bh / H_, h = bh - b * H_;
    const int tid = threadIdx.x;
    const float* vbase = v + (size_t)bh * N_ * HD_;
    for (int i = tid; i < N_ * HD_; i += 256) Vs[i] = vbase[i];
    __syncthreads();
    const int w = tid >> 6, lane = tid & 63;
    for (int r = w; r < N_; r += 4) {
        int st = srctok[(size_t)b * N_ + r];
        float accv = 0.f;
        if (st >= 0) {
            const bf16* ar = attn + ((size_t)bh * N_ + st) * N_;
#pragma unroll 4
            for (int m = 0; m < N_; ++m) accv += bf2f(ar[m]) * Vs[m * 64 + lane];
        }
        xo[((size_t)(b * N_) + r) * C_ + h * 64 + lane] = accv;
    }
}

// ---------------- launch ----------------
extern "C" void kernel_launch(void* const* d_in, const int* in_sizes, int n_in,
                              void* d_out, int out_size, void* d_ws, size_t ws_size,
                              hipStream_t stream) {
    // workspace layout (bytes); total ~225.0 MB (< r2's proven 243.6 MB)
    char* ws = (char*)d_ws;
    int*    flag    = (int*)   (ws + 0);            //        256
    double* w64     = (double*)(ws + 256);          // 14,155,776
    float*  wproj32 = (float*) (ws + 14156032);     //  2,359,296
    float*  wfc1_32 = (float*) (ws + 16515328);     //  9,437,184
    float*  wfc2_32 = (float*) (ws + 25952512);     //  9,437,184
    double* pol64   = (double*)(ws + 35389696);     //    100,864
    double* g1_64   = (double*)(ws + 35490560);     //      6,144
    double* b1_64   = (double*)(ws + 35496704);     //      6,144
    float*  g2_32   = (float*) (ws + 35502848);     //      3,072
    float*  b2_32   = (float*) (ws + 35505920);     //      3,072
    float*  bproj32 = (float*) (ws + 35508992);     //      3,072
    float*  bfc1_32 = (float*) (ws + 35512064);     //     12,288
    float*  bfc2_32 = (float*) (ws + 35524352);     //      3,072
    double* q0_64   = (double*)(ws + 35527424);     //    393,216
    double* wq0_64  = (double*)(ws + 35920640);     //  4,718,592
    double* vnorm2  = (double*)(ws + 40639232);     //    100,864
    double* cls64   = (double*)(ws + 40740096);     //  1,210,368
    double* score64 = (double*)(ws + 41950464);     //    100,352
    int*    srctok  = (int*)   (ws + 42050816);     //     50,432
    double* xn64    = (double*)(ws + 42101248);     // 77,463,552 [-> xo32 -> act]
    float*  q32     = (float*) (ws + 119564800);    // 12,910,592
    float*  k32     = (float*) (ws + 132475392);    // 12,910,592
    float*  v32     = (float*) (ws + 145385984);    // 12,910,592 [q/k/v -> h1_32]
    float*  xn32    = (float*) (ws + 158296576);    // 38,731,776 (attn slot; dead before attn write)
    bf16*   attn    = (bf16*)  (ws + 158296576);    // 59,610,624 [-> x2_32]
    float*  wqkv32  = (float*) (ws + 217907200);    //  7,077,888  (end: 224,985,088)
    float*  xo32    = (float*) (ws + 42101248);     // overlays xn64 (dead after cls)
    bf16*   act     = (bf16*)  (ws + 42101248);     // overlays xn64/xo32 (dead after proj)
    float*  h1_32   = (float*) (ws + 119564800);    // overlays q/k/v32 (dead after attn/av)
    float*  x2_32   = (float*) (ws + 158296576);    // overlays attn (dead after av)

    const dim3 blk(256);

    // 0) dtype detect, then flag-dispatched conversions + vnorm2 zero-init
    detect_kernel<<<1, blk, 0, stream>>>((const unsigned short*)d_in[2], flag);
    cvt64_kernel<<<1024, blk, 0, stream>>>(d_in[2],  w64,     C_ * C3_, flag);
    cvt32_kernel<<<1024, blk, 0, stream>>>(d_in[2],  wqkv32,  C_ * C3_, flag);
    cvt32_kernel<<<576,  blk, 0, stream>>>(d_in[3],  wproj32, C_ * C_,  flag);
    cvt32_kernel<<<3,    blk, 0, stream>>>(d_in[4],  bproj32, C_,       flag);
    cvt64_kernel<<<3,    blk, 0, stream>>>(d_in[5],  g1_64,   C_,       flag);
    cvt64_kernel<<<3,    blk, 0, stream>>>(d_in[6],  b1_64,   C_,       flag);
    cvt32_kernel<<<3,    blk, 0, stream>>>(d_in[7],  g2_32,   C_,       flag);
    cvt32_kernel<<<3,    blk, 0, stream>>>(d_in[8],  b2_32,   C_,       flag);
    cvt32_kernel<<<1024, blk, 0, stream>>>(d_in[9],  wfc1_32, C_ * C4_, flag);
    cvt32_kernel<<<12,   blk, 0, stream>>>(d_in[10], bfc1_32, C4_,      flag);
    cvt32_kernel<<<1024, blk, 0, stream>>>(d_in[11], wfc2_32, C4_ * C_, flag);
    cvt32_kernel<<<3,    blk, 0, stream>>>(d_in[12], bfc2_32, C_,       flag);
    cvt64_kernel<<<50,   blk, 0, stream>>>(d_in[1],  pol64,   M_,       flag);
    zero64_kernel<<<50,  blk, 0, stream>>>(vnorm2, M_);

    // 1) LN1 fp64 (+ fp32 copy into attn slot)
    ln64_kernel<<<M_, blk, 0, stream>>>(d_in[0], g1_64, b1_64, xn64, xn32, flag);

    // 2) fp64 score-path precursors
    q0_kernel<<<B_, blk, 0, stream>>>(xn64, w64, pol64, q0_64);
    wq0_kernel<<<B_, blk, 0, stream>>>(w64, q0_64, wq0_64);

    // 3) q,k fp32 GEMM (bit-identical values, now fp32 inputs + conflict-free LDS reads)
    { Epi e = {}; e.qq = q32; e.kk = k32; e.pol = pol64;
      gemm_k<0, float><<<dim3(12, (M_ + 127) / 128), blk, 0, stream>>>(xn32, wqkv32, M_, C3_, C_, e); }

    // 4) v fp64 GEMM (score-critical) -> v32 + vnorm2
    gemm64_v<<<dim3(C_ / 64, M_ / 64), blk, 0, stream>>>(xn64, w64, pol64, v32, vnorm2);

    // 5) cls rows fp64 (block per batch, wave-parallel)
    cls_kernel<<<B_, blk, 0, stream>>>(xn64, wq0_64, pol64, cls64);

    // 6) attention probs fp32 -> bf16 (overwrites xn32 region)
    attn_kernel<<<BH_, blk, 0, stream>>>(q32, k32, pol64, attn);

    // 7) score + sampling (fp64)
    score_kernel<<<B_, blk, 0, stream>>>(cls64, vnorm2, score64);
    sample_kernel<<<B_, blk, 0, stream>>>(score64, srctok);

    // 8) xo = gathered attn @ v  (into xn64 slot)
    av_kernel<<<BH_, blk, 0, stream>>>(attn, v32, srctok, xo32);

    // 9) proj -> x2 (attn slot)
    { Epi e = {}; e.bias = bproj32; e.srctok = srctok; e.xin = d_in[0]; e.x2out = x2_32; e.flagp = flag;
      gemm_k<1, float><<<dim3(C_ / 128, (M_ + 127) / 128), blk, 0, stream>>>(xo32, wproj32, M_, C_, C_, e); }

    // 10) LN2 fp32 -> h1 (q/k/v slot)
    ln32_kernel<<<M_, blk, 0, stream>>>(x2_32, g2_32, b2_32, h1_32);

    // 11) fc1 + GELU -> act bf16 (xn64 slot)
    { Epi e = {}; e.bias = bfc1_32; e.act = act;
      gemm_k<2, float><<<dim3(C4_ / 128, (M_ + 127) / 128), blk, 0, stream>>>(h1_32, wfc1_32, M_, C4_, C_, e); }

    // 12) fc2 + residual + pol -> out (dtype per flag)
    { Epi e = {}; e.bias = bfc2_32; e.srctok = srctok; e.x2in = x2_32; e.dout = d_out; e.flagp = flag;
      gemm_k<3, bf16><<<dim3(C_ / 128, (M_ + 127) / 128), blk, 0, stream>>>(act, wfc2_32, M_, C_, C4_, e); }
}

// Round 6
// 2988.035 us; speedup vs baseline: 1.7397x; 1.5547x over previous
//
#include <hip/hip_runtime.h>
#include <hip/hip_bf16.h>
#include <cmath>

typedef __hip_bfloat16 bf16;
typedef unsigned short ushort_t;
typedef __attribute__((ext_vector_type(8))) short short8;
typedef __attribute__((ext_vector_type(4))) float floatx4;
#define DEV static __device__ __forceinline__

DEV float bf2f(bf16 x) { return __bfloat162float(x); }
DEV bf16  f2bf(float x) { return __float2bfloat16(x); }

constexpr int B_  = 64, N_ = 197, C_ = 768, H_ = 12, HD_ = 64;
constexpr int C3_ = 3 * C_;      // 2304
constexpr int C4_ = 4 * C_;      // 3072
constexpr int M_  = B_ * N_;     // 12608
constexpr int BH_ = B_ * H_;     // 768
constexpr int NM1 = N_ - 1;      // 196

DEV ushort_t bfbits(bf16 b) { union { bf16 b; ushort_t u; } cv; cv.b = b; return cv.u; }
DEV void split_bf(float x, ushort_t& h, ushort_t& l) {
    bf16 bh = f2bf(x);
    float fh = bf2f(bh);
    bf16 bl = f2bf(x - fh);
    h = bfbits(bh); l = bfbits(bl);
}

// ---------------- dtype detection ----------------
__global__ __launch_bounds__(256) void detect_kernel(const ushort_t* __restrict__ w,
                                                     int* __restrict__ flag) {
    __shared__ int cnt;
    if (threadIdx.x == 0) cnt = 0;
    __syncthreads();
    int c = 0;
#pragma unroll
    for (int k = 0; k < 8; ++k) {
        ushort_t u = w[threadIdx.x * 8 + k];
        int e = (u >> 7) & 0xFF;
        if (e >= 143) ++c;
    }
    atomicAdd(&cnt, c);
    __syncthreads();
    if (threadIdx.x == 0) *flag = (cnt >= 8) ? 1 : 0;   // 1 = fp32 inputs
}

DEV float load_in(const void* p, size_t i, bool f32) {
    return f32 ? ((const float*)p)[i] : bf2f(((const bf16*)p)[i]);
}

// ---------------- converters ----------------
__global__ __launch_bounds__(256) void cvt32_kernel(const void* __restrict__ s, float* __restrict__ d,
                                                    int n, const int* __restrict__ flag) {
    const bool f32 = (*flag != 0);
    int i = blockIdx.x * 256 + threadIdx.x, st = gridDim.x * 256;
    for (; i < n; i += st) d[i] = load_in(s, i, f32);
}
__global__ __launch_bounds__(256) void cvt64_kernel(const void* __restrict__ s, double* __restrict__ d,
                                                    int n, const int* __restrict__ flag) {
    const bool f32 = (*flag != 0);
    int i = blockIdx.x * 256 + threadIdx.x, st = gridDim.x * 256;
    for (; i < n; i += st) d[i] = (double)load_in(s, i, f32);
}
__global__ __launch_bounds__(256) void zero64_kernel(double* __restrict__ d, int n) {
    int i = blockIdx.x * 256 + threadIdx.x, st = gridDim.x * 256;
    for (; i < n; i += st) d[i] = 0.0;
}

// ---------------- weight transpose + split: W[K][Nstride] -> WT_hi/lo [Ncols][K] ----------------
__global__ __launch_bounds__(256) void tsplit_kernel(const void* __restrict__ W,
                                                     int K, int Nstride,
                                                     ushort_t* __restrict__ hi,
                                                     ushort_t* __restrict__ lo,
                                                     const int* __restrict__ flag) {
    __shared__ float t[32][33];
    const bool f32 = (*flag != 0);
    const int tid = threadIdx.x;
    const int n0 = blockIdx.x * 32, k0 = blockIdx.y * 32;
    for (int idx = tid; idx < 1024; idx += 256) {
        int kk = idx >> 5, nn = idx & 31;
        t[kk][nn] = load_in(W, (size_t)(k0 + kk) * Nstride + n0 + nn, f32);
    }
    __syncthreads();
    for (int idx = tid; idx < 1024; idx += 256) {
        int nn = idx >> 5, kk = idx & 31;
        ushort_t h, l; split_bf(t[kk][nn], h, l);
        size_t o = (size_t)(n0 + nn) * K + k0 + kk;
        hi[o] = h; lo[o] = l;
    }
}

// ---------------- block reductions ----------------
DEV double bred_sum64(double v, double* red) {
    int t = threadIdx.x; red[t] = v; __syncthreads();
    for (int s = 128; s > 0; s >>= 1) { if (t < s) red[t] += red[t + s]; __syncthreads(); }
    double r = red[0]; __syncthreads(); return r;
}
DEV double bred_min64(double v, double* red) {
    int t = threadIdx.x; red[t] = v; __syncthreads();
    for (int s = 128; s > 0; s >>= 1) { if (t < s) red[t] = fmin(red[t], red[t + s]); __syncthreads(); }
    double r = red[0]; __syncthreads(); return r;
}
DEV float bred_sum32(float v, float* red) {
    int t = threadIdx.x; red[t] = v; __syncthreads();
    for (int s = 128; s > 0; s >>= 1) { if (t < s) red[t] += red[t + s]; __syncthreads(); }
    float r = red[0]; __syncthreads(); return r;
}

// ---------------- LN1 fp64: raw x -> xn64 + xn hi/lo ----------------
__global__ __launch_bounds__(256) void ln64_kernel(const void* __restrict__ in,
                                                   const double* __restrict__ g,
                                                   const double* __restrict__ bb,
                                                   double* __restrict__ out,
                                                   ushort_t* __restrict__ oh,
                                                   ushort_t* __restrict__ ol,
                                                   const int* __restrict__ flag) {
    __shared__ double red[256];
    const bool f32 = (*flag != 0);
    const int tid = threadIdx.x;
    const size_t row = blockIdx.x;
    double x0 = (double)load_in(in, row * C_ + tid, f32);
    double x1 = (double)load_in(in, row * C_ + tid + 256, f32);
    double x2 = (double)load_in(in, row * C_ + tid + 512, f32);
    double m = bred_sum64(x0 + x1 + x2, red) / 768.0;
    double d0 = x0 - m, d1 = x1 - m, d2 = x2 - m;
    double var = bred_sum64(d0 * d0 + d1 * d1 + d2 * d2, red) / 768.0;
    double istd = 1.0 / sqrt(var + 1e-5);
    double* op = out + row * C_;
    double v0 = (d0 * istd) * g[tid]     + bb[tid];
    double v1 = (d1 * istd) * g[tid+256] + bb[tid+256];
    double v2 = (d2 * istd) * g[tid+512] + bb[tid+512];
    op[tid] = v0; op[tid+256] = v1; op[tid+512] = v2;
    ushort_t h, l;
    split_bf((float)v0, h, l); oh[row*C_+tid]     = h; ol[row*C_+tid]     = l;
    split_bf((float)v1, h, l); oh[row*C_+tid+256] = h; ol[row*C_+tid+256] = l;
    split_bf((float)v2, h, l); oh[row*C_+tid+512] = h; ol[row*C_+tid+512] = l;
}

// ---------------- LN2 fp32 -> h1 hi/lo ----------------
__global__ __launch_bounds__(256) void ln32_kernel(const float* __restrict__ in,
                                                   const float* __restrict__ g,
                                                   const float* __restrict__ bb,
                                                   ushort_t* __restrict__ oh,
                                                   ushort_t* __restrict__ ol) {
    __shared__ float red[256];
    const int tid = threadIdx.x;
    const size_t row = blockIdx.x;
    const float* xp = in + row * C_;
    float x0 = xp[tid], x1 = xp[tid + 256], x2 = xp[tid + 512];
    float m = bred_sum32(x0 + x1 + x2, red) * (1.0f / 768.0f);
    float d0 = x0 - m, d1 = x1 - m, d2 = x2 - m;
    float var = bred_sum32(d0 * d0 + d1 * d1 + d2 * d2, red) * (1.0f / 768.0f);
    float istd = 1.0f / sqrtf(var + 1e-5f);
    ushort_t h, l;
    split_bf(d0 * istd * g[tid]     + bb[tid],     h, l); oh[row*C_+tid]     = h; ol[row*C_+tid]     = l;
    split_bf(d1 * istd * g[tid+256] + bb[tid+256], h, l); oh[row*C_+tid+256] = h; ol[row*C_+tid+256] = l;
    split_bf(d2 * istd * g[tid+512] + bb[tid+512], h, l); oh[row*C_+tid+512] = h; ol[row*C_+tid+512] = l;
}

// ---------------- q0 / wq0 / cls (decision path, verbatim) ----------------
__global__ __launch_bounds__(256) void q0_kernel(const double* __restrict__ xn64,
                                                 const double* __restrict__ w64,
                                                 const double* __restrict__ pol,
                                                 double* __restrict__ q0) {
    const int b = blockIdx.x, tid = threadIdx.x;
    const double* xr = xn64 + (size_t)(b * N_) * C_;
    double p0 = pol[b * N_];
    for (int j = tid; j < C_; j += 256) {
        double acc = 0.0;
        for (int c = 0; c < C_; ++c) acc += xr[c] * w64[(size_t)c * C3_ + j];
        q0[(size_t)b * C_ + j] = acc * p0;
    }
}

__global__ __launch_bounds__(256) void wq0_kernel(const double* __restrict__ w64,
                                                  const double* __restrict__ q0,
                                                  double* __restrict__ wq0) {
    const int b = blockIdx.x, tid = threadIdx.x;
    for (int idx = tid; idx < H_ * C_; idx += 256) {
        int h = idx / C_, c = idx - h * C_;
        const double* wr = w64 + (size_t)c * C3_ + C_ + h * HD_;
        const double* qr = q0 + (size_t)b * C_ + h * HD_;
        double acc = 0.0;
#pragma unroll 8
        for (int d = 0; d < HD_; ++d) acc += wr[d] * qr[d];
        wq0[((size_t)b * H_ + h) * C_ + c] = acc;
    }
}

__global__ __launch_bounds__(256) void cls_kernel(const double* __restrict__ xn64,
                                                  const double* __restrict__ wq0,
                                                  const double* __restrict__ pol,
                                                  double* __restrict__ cls) {
    __shared__ double wsh[6][768];
    __shared__ double sarr[6][200];
    const int b = blockIdx.x;
    const int tid = threadIdx.x, w = tid >> 6, lane = tid & 63;
    for (int ph = 0; ph < 2; ++ph) {
        for (int idx = tid; idx < 6 * 768; idx += 256) {
            int h = idx / 768, c = idx - h * 768;
            wsh[h][c] = wq0[((size_t)b * H_ + ph * 6 + h) * C_ + c];
        }
        __syncthreads();
        for (int t = w; t < N_; t += 4) {
            const double* xr = xn64 + (size_t)(b * N_ + t) * C_;
            double xreg[12];
#pragma unroll
            for (int ch = 0; ch < 12; ++ch) xreg[ch] = xr[ch * 64 + lane];
            double pm = pol[b * N_ + t] * 0.125;
            for (int h = 0; h < 6; ++h) {
                double acc = 0.0;
#pragma unroll
                for (int ch = 0; ch < 12; ++ch) acc += xreg[ch] * wsh[h][ch * 64 + lane];
                for (int off = 32; off > 0; off >>= 1) acc += __shfl_down(acc, off, 64);
                if (lane == 0) sarr[h][t] = acc * pm;
            }
        }
        __syncthreads();
        for (int hh = w; hh < 6; hh += 4) {
            const int j0 = lane, j1 = lane + 64, j2 = lane + 128, j3 = lane + 192;
            const bool h3 = (lane < 5);
            double s0 = sarr[hh][j0], s1 = sarr[hh][j1], s2 = sarr[hh][j2];
            double s3 = h3 ? sarr[hh][j3] : -INFINITY;
            double m = fmax(fmax(s0, s2), fmax(s1, s3));
            for (int off = 32; off > 0; off >>= 1) m = fmax(m, __shfl_down(m, off, 64));
            double mx = __shfl(m, 0, 64);
            double p0 = pol[b * N_ + j0], p1 = pol[b * N_ + j1], p2 = pol[b * N_ + j2];
            double e0 = exp(s0 - mx) * (p0 + (1.0 - p0));
            if (j0 != 0) e0 = exp(s0 - mx) * p0;
            double e1 = exp(s1 - mx) * p1;
            double e2 = exp(s2 - mx) * p2;
            double e3 = 0.0;
            if (h3) { double p3 = pol[b * N_ + j3]; e3 = exp(s3 - mx) * p3; }
            double su = (e0 + e2) + (e1 + e3);
            for (int off = 32; off > 0; off >>= 1) su += __shfl_down(su, off, 64);
            double ssum = __shfl(su, 0, 64);
            double* crow = cls + ((size_t)b * H_ + ph * 6 + hh) * N_;
            crow[j0] = (e0 + 1e-6 / 197.0) / (ssum + 1e-6);
            crow[j1] = (e1 + 1e-6 / 197.0) / (ssum + 1e-6);
            crow[j2] = (e2 + 1e-6 / 197.0) / (ssum + 1e-6);
            if (h3) crow[j3] = (e3 + 1e-6 / 197.0) / (ssum + 1e-6);
        }
        __syncthreads();
    }
}

// ---------------- fp64 GEMM for V (decision path, verbatim) ----------------
__global__ __launch_bounds__(256) void gemm64_v(const double* __restrict__ A,
                                                const double* __restrict__ W,
                                                const double* __restrict__ pol,
                                                float* __restrict__ v32,
                                                double* __restrict__ vnorm2) {
    __shared__ double As[16][65];
    __shared__ double Bs[16][68];
    const int tid = threadIdx.x;
    const int tx = tid & 15, ty = tid >> 4;
    const int bx = blockIdx.x, by = blockIdx.y;
    const int arow = tid & 63, ak = (tid >> 6) * 4;
    const int brow = tid >> 4, bcol = (tid & 15) * 4;

    double acc[4][4];
#pragma unroll
    for (int i = 0; i < 4; ++i)
#pragma unroll
        for (int j = 0; j < 4; ++j) acc[i][j] = 0.0;

    const int gr = by * 64 + arow;
    for (int k0 = 0; k0 < C_; k0 += 16) {
        const double* ap = A + (size_t)gr * C_ + k0 + ak;
        double a0 = ap[0], a1 = ap[1], a2 = ap[2], a3 = ap[3];
        const double* bp = W + (size_t)(k0 + brow) * C3_ + 2 * C_ + bx * 64 + bcol;
        double b0 = bp[0], b1 = bp[1], b2 = bp[2], b3 = bp[3];
        __syncthreads();
        As[ak + 0][arow] = a0; As[ak + 1][arow] = a1; As[ak + 2][arow] = a2; As[ak + 3][arow] = a3;
        Bs[brow][bcol + 0] = b0; Bs[brow][bcol + 1] = b1; Bs[brow][bcol + 2] = b2; Bs[brow][bcol + 3] = b3;
        __syncthreads();
#pragma unroll
        for (int kk = 0; kk < 16; ++kk) {
            double aa[4], bb[4];
#pragma unroll
            for (int i = 0; i < 4; ++i) aa[i] = As[kk][ty * 4 + i];
#pragma unroll
            for (int j = 0; j < 4; ++j) bb[j] = Bs[kk][tx * 4 + j];
#pragma unroll
            for (int i = 0; i < 4; ++i)
#pragma unroll
                for (int j = 0; j < 4; ++j) acc[i][j] += aa[i] * bb[j];
        }
    }
    const int col0 = bx * 64 + tx * 4;
    const int h = col0 >> 6, d0 = col0 & 63;
#pragma unroll
    for (int i = 0; i < 4; ++i) {
        int row = by * 64 + ty * 4 + i;
        int b = row / N_, nn = row - b * N_;
        double p = pol[row];
        double s2 = 0.0;
        float* dst = v32 + (((size_t)(b * H_ + h)) * N_ + nn) * HD_ + d0;
#pragma unroll
        for (int j = 0; j < 4; ++j) {
            double vv = acc[i][j] * p;
            dst[j] = (float)vv;
            s2 += vv * vv;
        }
        atomicAdd(&vnorm2[row], s2);
    }
}

// ---------------- MFMA split-bf16 GEMM: 128x128 tile, K-step 32 ----------------
struct Epi {
    const float* bias;
    const int* srctok;
    const void* xin;
    float* x2out;
    bf16* act;
    const float* x2in;
    void* dout;
    const int* flagp;
    float* qq; float* kk;
    const double* pol;
};

// MODE: 0 = qk scatter, 1 = proj -> x2, 2 = fc1 gelu -> act bf16, 3 = fc2 -> out
template <int MODE, bool SPLITA>
__global__ __launch_bounds__(256) void mgemm(const ushort_t* __restrict__ Ah,
                                             const ushort_t* __restrict__ Al,
                                             const ushort_t* __restrict__ Bh,
                                             const ushort_t* __restrict__ Bl,
                                             int M, int K, Epi ep) {
    __shared__ ushort_t As_h[4096];
    __shared__ ushort_t As_l[4096];
    __shared__ ushort_t Bs_h[4096];
    __shared__ ushort_t Bs_l[4096];
    const int tid = threadIdx.x;
    const int lane = tid & 63, w = tid >> 6;
    const int wr = w >> 1, wc = w & 1;
    const int quad = lane >> 4, mn = lane & 15;
    const int row0 = blockIdx.y * 128, col0 = blockIdx.x * 128;

    floatx4 acc[4][4];
#pragma unroll
    for (int i = 0; i < 4; ++i)
#pragma unroll
        for (int j = 0; j < 4; ++j) acc[i][j] = floatx4{0.f, 0.f, 0.f, 0.f};

    const int srow = tid >> 2, soct = tid & 3;       // s=0 chunk
    const int srow2 = (tid + 256) >> 2;              // s=1 chunk (oct same)
    const int dst1 = (((srow >> 4) * 4 + soct) * 16 + (srow & 15)) * 8;
    const int dst2 = (((srow2 >> 4) * 4 + soct) * 16 + (srow2 & 15)) * 8;

    for (int k0 = 0; k0 < K; k0 += 32) {
        uint4 ah1, ah2, al1, al2, bh1, bh2, bl1, bl2;
        const uint4 zz = make_uint4(0, 0, 0, 0);
        {
            int gr = row0 + srow;
            size_t go = (size_t)gr * K + k0 + soct * 8;
            if (gr < M) { ah1 = *(const uint4*)(Ah + go); al1 = SPLITA ? *(const uint4*)(Al + go) : zz; }
            else        { ah1 = zz; al1 = zz; }
            gr = row0 + srow2;
            go = (size_t)gr * K + k0 + soct * 8;
            if (gr < M) { ah2 = *(const uint4*)(Ah + go); al2 = SPLITA ? *(const uint4*)(Al + go) : zz; }
            else        { ah2 = zz; al2 = zz; }
            size_t bo = (size_t)(col0 + srow) * K + k0 + soct * 8;
            bh1 = *(const uint4*)(Bh + bo); bl1 = *(const uint4*)(Bl + bo);
            bo = (size_t)(col0 + srow2) * K + k0 + soct * 8;
            bh2 = *(const uint4*)(Bh + bo); bl2 = *(const uint4*)(Bl + bo);
        }
        __syncthreads();
        *(uint4*)(As_h + dst1) = ah1; *(uint4*)(As_h + dst2) = ah2;
        if (SPLITA) { *(uint4*)(As_l + dst1) = al1; *(uint4*)(As_l + dst2) = al2; }
        *(uint4*)(Bs_h + dst1) = bh1; *(uint4*)(Bs_h + dst2) = bh2;
        *(uint4*)(Bs_l + dst1) = bl1; *(uint4*)(Bs_l + dst2) = bl2;
        __syncthreads();

        short8 afh[4], afl[4], bfh[4], bfl[4];
#pragma unroll
        for (int i = 0; i < 4; ++i) {
            int off = ((wr * 4 + i) * 64 + lane) * 8;
            afh[i] = *(const short8*)(As_h + off);
            if (SPLITA) afl[i] = *(const short8*)(As_l + off);
        }
#pragma unroll
        for (int j = 0; j < 4; ++j) {
            int off = ((wc * 4 + j) * 64 + lane) * 8;
            bfh[j] = *(const short8*)(Bs_h + off);
            bfl[j] = *(const short8*)(Bs_l + off);
        }
#pragma unroll
        for (int i = 0; i < 4; ++i)
#pragma unroll
            for (int j = 0; j < 4; ++j) {
                acc[i][j] = __builtin_amdgcn_mfma_f32_16x16x32_bf16(afh[i], bfh[j], acc[i][j], 0, 0, 0);
                acc[i][j] = __builtin_amdgcn_mfma_f32_16x16x32_bf16(afh[i], bfl[j], acc[i][j], 0, 0, 0);
                if (SPLITA)
                    acc[i][j] = __builtin_amdgcn_mfma_f32_16x16x32_bf16(afl[i], bfh[j], acc[i][j], 0, 0, 0);
            }
    }

    // epilogue: element (i,j,r): row = row0+wr*64+i*16+quad*4+r, col = col0+wc*64+j*16+mn
    if constexpr (MODE == 0) {
#pragma unroll
        for (int j = 0; j < 4; ++j) {
            int col = col0 + wc * 64 + j * 16 + mn;
            int comp = (col >= C_) ? 1 : 0;
            int rem = col - comp * C_;
            int hh = rem >> 6, d0 = rem & 63;
            float* dstbase = comp ? ep.kk : ep.qq;
#pragma unroll
            for (int i = 0; i < 4; ++i) {
                int rbase = row0 + wr * 64 + i * 16 + quad * 4;
#pragma unroll
                for (int r = 0; r < 4; ++r) {
                    int row = rbase + r; if (row >= M) continue;
                    int b = row / N_, nn = row - b * N_;
                    float pv = (float)ep.pol[row];
                    dstbase[(((size_t)(b * H_ + hh)) * N_ + nn) * HD_ + d0] = acc[i][j][r] * pv;
                }
            }
        }
    } else if constexpr (MODE == 1) {
        const bool f32 = (*ep.flagp != 0);
#pragma unroll
        for (int i = 0; i < 4; ++i) {
            int rbase = row0 + wr * 64 + i * 16 + quad * 4;
#pragma unroll
            for (int r = 0; r < 4; ++r) {
                int row = rbase + r; if (row >= M) continue;
                int st = ep.srctok[row];
                float polv = (st >= 0) ? 1.f : 0.f;
                int b = row / N_;
                size_t xrow = ((size_t)(b * N_ + (st < 0 ? 0 : st))) * C_;
#pragma unroll
                for (int j = 0; j < 4; ++j) {
                    int col = col0 + wc * 64 + j * 16 + mn;
                    float selx = (st >= 0) ? load_in(ep.xin, xrow + col, f32) : 0.f;
                    ep.x2out[(size_t)row * C_ + col] = selx + (acc[i][j][r] + ep.bias[col]) * polv;
                }
            }
        }
    } else if constexpr (MODE == 2) {
#pragma unroll
        for (int i = 0; i < 4; ++i) {
            int rbase = row0 + wr * 64 + i * 16 + quad * 4;
#pragma unroll
            for (int r = 0; r < 4; ++r) {
                int row = rbase + r; if (row >= M) continue;
#pragma unroll
                for (int j = 0; j < 4; ++j) {
                    int col = col0 + wc * 64 + j * 16 + mn;
                    float z = acc[i][j][r] + ep.bias[col];
                    float gl = 0.5f * z * (1.0f + erff(z * 0.70710678118654752f));
                    ep.act[(size_t)row * C4_ + col] = f2bf(gl);
                }
            }
        }
    } else {
        const bool f32out = (*ep.flagp != 0);
#pragma unroll
        for (int i = 0; i < 4; ++i) {
            int rbase = row0 + wr * 64 + i * 16 + quad * 4;
#pragma unroll
            for (int r = 0; r < 4; ++r) {
                int row = rbase + r; if (row >= M) continue;
                int st = ep.srctok[row];
                float polv = (st >= 0) ? 1.f : 0.f;
#pragma unroll
                for (int j = 0; j < 4; ++j) {
                    int col = col0 + wc * 64 + j * 16 + mn;
                    float val = (ep.x2in[(size_t)row * C_ + col] + acc[i][j][r] + ep.bias[col]) * polv;
                    size_t o = (size_t)row * C_ + col;
                    if (f32out) ((float*)ep.dout)[o] = val;
                    else        ((bf16*)ep.dout)[o] = f2bf(val);
                }
            }
        }
    }
}

// ---------------- attention probs (verbatim from r5) ----------------
__global__ __launch_bounds__(256) void attn_kernel(const float* __restrict__ q,
                                                   const float* __restrict__ k,
                                                   const double* __restrict__ policy,
                                                   bf16* __restrict__ attn) {
    __shared__ float Ks[197 * 69];
    __shared__ float ps[256];
    const int bh = blockIdx.x, b = bh / H_;
    const int tid = threadIdx.x;
    const float* kbase = k + (size_t)bh * N_ * HD_;
    for (int idx = tid; idx < N_ * HD_; idx += 256) Ks[(idx >> 6) * 69 + (idx & 63)] = kbase[idx];
    for (int j = tid; j < 256; j += 256) ps[j] = (j < N_) ? (float)policy[b * N_ + j] : 0.f;
    __syncthreads();
    const int w = tid >> 6, lane = tid & 63;
    const int j0 = lane, j1 = lane + 64, j2 = lane + 128, j3 = lane + 192;
    const bool h3 = (lane < 5);
    const float* k0p = &Ks[j0 * 69];
    const float* k1p = &Ks[j1 * 69];
    const float* k2p = &Ks[j2 * 69];
    const float* k3p = h3 ? &Ks[j3 * 69] : &Ks[j0 * 69];
    const float p0 = ps[j0], p1 = ps[j1], p2 = ps[j2], p3 = h3 ? ps[j3] : 0.f;
    const float* qbase = q + (size_t)bh * N_ * HD_;
    for (int i = w; i < N_; i += 4) {
        const float* qr = qbase + i * HD_;
        float a0 = 0.f, a1 = 0.f, a2 = 0.f, a3 = 0.f;
#pragma unroll 8
        for (int d = 0; d < 64; ++d) {
            float qd = qr[d];
            a0 += qd * k0p[d]; a1 += qd * k1p[d]; a2 += qd * k2p[d]; a3 += qd * k3p[d];
        }
        float s0 = a0 * 0.125f, s1 = a1 * 0.125f, s2 = a2 * 0.125f;
        float s3 = h3 ? a3 * 0.125f : -INFINITY;
        float m = fmaxf(fmaxf(s0, s2), fmaxf(s1, s3));
        for (int off = 32; off > 0; off >>= 1) m = fmaxf(m, __shfl_down(m, off, 64));
        float mx = __shfl(m, 0, 64);
        float e0 = expf(s0 - mx) * (p0 + (1.f - p0) * ((j0 == i) ? 1.f : 0.f));
        float e1 = expf(s1 - mx) * (p1 + (1.f - p1) * ((j1 == i) ? 1.f : 0.f));
        float e2 = expf(s2 - mx) * (p2 + (1.f - p2) * ((j2 == i) ? 1.f : 0.f));
        float e3 = h3 ? expf(s3 - mx) * (p3 + (1.f - p3) * ((j3 == i) ? 1.f : 0.f)) : 0.f;
        float su = (e0 + e2) + (e1 + e3);
        for (int off = 32; off > 0; off >>= 1) su += __shfl_down(su, off, 64);
        float ssum = __shfl(su, 0, 64);
        bf16* orow = attn + ((size_t)bh * N_ + i) * N_;
        orow[j0] = f2bf((e0 + 5.0761421319796954e-9f) / (ssum + 1e-6f));
        orow[j1] = f2bf((e1 + 5.0761421319796954e-9f) / (ssum + 1e-6f));
        orow[j2] = f2bf((e2 + 5.0761421319796954e-9f) / (ssum + 1e-6f));
        if (h3) orow[j3] = f2bf((e3 + 5.0761421319796954e-9f) / (ssum + 1e-6f));
    }
}

// ---------------- score / sampling (decision path, verbatim) ----------------
__global__ __launch_bounds__(256) void score_kernel(const double* __restrict__ cls,
                                                    const double* __restrict__ vnorm2,
                                                    double* __restrict__ score) {
    __shared__ double red[256];
    const int b = blockIdx.x, t = threadIdx.x;
    double raw = 0.0;
    if (t < N_) {
        double cs = 0.0;
        for (int h = 0; h < H_; ++h) cs += cls[(size_t)(b * H_ + h) * N_ + t];
        raw = cs * sqrt(vnorm2[b * N_ + t]);
    }
    double contrib = (t >= 1 && t < N_) ? raw : 0.0;
    double tot = bred_sum64(contrib, red);
    if (t >= 1 && t < N_) score[(size_t)b * NM1 + (t - 1)] = raw / tot;
}

DEV void bitonic_fi64(double* key, int* idx) {
    const int tid = threadIdx.x;
    for (int ksz = 2; ksz <= 256; ksz <<= 1)
        for (int jj = ksz >> 1; jj > 0; jj >>= 1) {
            __syncthreads();
            int ixj = tid ^ jj;
            if (ixj > tid) {
                double ka = key[tid], kb = key[ixj];
                int ia = idx[tid], ib = idx[ixj];
                bool up = (tid & ksz) == 0;
                bool agtb = (ka > kb) || (ka == kb && ia > ib);
                if (agtb == up) { key[tid] = kb; key[ixj] = ka; idx[tid] = ib; idx[ixj] = ia; }
            }
        }
    __syncthreads();
}
DEV void bitonic_int(int* a) {
    const int tid = threadIdx.x;
    for (int ksz = 2; ksz <= 256; ksz <<= 1)
        for (int jj = ksz >> 1; jj > 0; jj >>= 1) {
            __syncthreads();
            int ixj = tid ^ jj;
            if (ixj > tid) {
                int va = a[tid], vb = a[ixj];
                bool up = (tid & ksz) == 0;
                if ((va > vb) == up) { a[tid] = vb; a[ixj] = va; }
            }
        }
    __syncthreads();
}

__global__ __launch_bounds__(256) void sample_kernel(const double* __restrict__ score,
                                                     int* __restrict__ srctok) {
    __shared__ double key[256];
    __shared__ int   idx[256];
    __shared__ double ncdf[196];
    __shared__ double red[256];
    __shared__ int   s1[256];
    __shared__ int   s2[256];
    __shared__ double cmm[2];
    const int b = blockIdx.x, tid = threadIdx.x;

    key[tid] = (tid < NM1) ? score[(size_t)b * NM1 + tid] : INFINITY;
    idx[tid] = tid;
    __syncthreads();
    bitonic_fi64(key, idx);

    if (tid == 0) {
        double c = 0.0, mn = INFINITY, mx = -INFINITY;
        for (int j = 0; j < NM1; ++j) {
            c += key[j]; ncdf[j] = c;
            mn = fmin(mn, c); mx = fmax(mx, c);
        }
        cmm[0] = mn; cmm[1] = mx;
    }
    __syncthreads();
    double cmin = cmm[0], cmax = cmm[1];
    if (tid < NM1) ncdf[tid] = (ncdf[tid] - cmin) / (cmax - cmin);
    __syncthreads();

    double vsm = (tid < NM1) ? (ncdf[tid] + ((ncdf[tid] == 0.0) ? 1e8 : 0.0)) : INFINITY;
    double ys_start = bred_min64(vsm, red);

    int tp = 0x7fffffff;
    if (tid < NM1) {
        double yj = (tid == 195) ? 1.0 : (double)tid * (1.0 / 195.0);
        double ys = ys_start + (yj * 195.0 - ys_start * (double)tid) / 195.0;
        double best = fabs(ys - ncdf[0]); int bj = 0;
        for (int j = 1; j < NM1; ++j) {
            double d = fabs(ys - ncdf[j]);
            if (d < best) { best = d; bj = j; }
        }
        tp = bj;
    }
    s1[tid] = tp; __syncthreads();
    bitonic_int(s1);

    int u = 0x7fffffff;
    if (tid < NM1) {
        int sv = s1[tid];
        int nxt = (tid < NM1 - 1) ? s1[tid + 1] : 1;
        u = (nxt == sv) ? NM1 : sv;
    }
    __syncthreads();
    s2[tid] = u; __syncthreads();
    bitonic_int(s2);

    if (tid < N_) {
        int st;
        if (tid == 0) st = 0;
        else {
            int uu = s2[tid - 1];
            st = (uu == NM1) ? -1 : (1 + idx[uu]);
        }
        srctok[(size_t)b * N_ + tid] = st;
    }
}

// ---------------- xo = gathered_attn @ v, split output ----------------
__global__ __launch_bounds__(256) void av_kernel(const bf16* __restrict__ attn,
                                                 const float* __restrict__ v,
                                                 const int* __restrict__ srctok,
                                                 ushort_t* __restrict__ xoh,
                                                 ushort_t* __restrict__ xol) {
    __shared__ float Vs[197 * 64];
    const int bh = blockIdx.x;
    const int b = bh / H_, hd = bh - b * H_;
    const int tid = threadIdx.x;
    const float* vbase = v + (size_t)bh * N_ * HD_;
    for (int i = tid; i < N_ * HD_; i += 256) Vs[i] = vbase[i];
    __syncthreads();
    const int w = tid >> 6, lane = tid & 63;
    for (int r = w; r < N_; r += 4) {
        int st = srctok[(size_t)b * N_ + r];
        float accv = 0.f;
        if (st >= 0) {
            const bf16* ar = attn + ((size_t)bh * N_ + st) * N_;
#pragma unroll 4
            for (int m = 0; m < N_; ++m) accv += bf2f(ar[m]) * Vs[m * 64 + lane];
        }
        ushort_t h, l; split_bf(accv, h, l);
        size_t o = ((size_t)(b * N_) + r) * C_ + hd * 64 + lane;
        xoh[o] = h; xol[o] = l;
    }
}

// ---------------- launch ----------------
extern "C" void kernel_launch(void* const* d_in, const int* in_sizes, int n_in,
                              void* d_out, int out_size, void* d_ws, size_t ws_size,
                              hipStream_t stream) {
    char* ws = (char*)d_ws;
    int*      flag     = (int*)     (ws + 0);
    double*   w64      = (double*)  (ws + 256);          // 14,155,776
    ushort_t* wqkvT_h  = (ushort_t*)(ws + 14156032);     //  2,359,296
    ushort_t* wqkvT_l  = (ushort_t*)(ws + 16515328);     //  2,359,296
    ushort_t* wprojT_h = (ushort_t*)(ws + 18874624);     //  1,179,648
    ushort_t* wprojT_l = (ushort_t*)(ws + 20054272);     //  1,179,648
    ushort_t* wfc1T_h  = (ushort_t*)(ws + 21233920);     //  4,718,592
    ushort_t* wfc1T_l  = (ushort_t*)(ws + 25952512);     //  4,718,592
    ushort_t* wfc2T_h  = (ushort_t*)(ws + 30671104);     //  4,718,592
    ushort_t* wfc2T_l  = (ushort_t*)(ws + 35389696);     //  4,718,592
    double*   pol64    = (double*)  (ws + 40108288);     //    100,864
    double*   g1_64    = (double*)  (ws + 40209152);     //      6,144
    double*   b1_64    = (double*)  (ws + 40215296);     //      6,144
    float*    g2_32    = (float*)   (ws + 40221440);     //      3,072
    float*    b2_32    = (float*)   (ws + 40224512);     //      3,072
    float*    bproj32  = (float*)   (ws + 40227584);     //      3,072
    float*    bfc1_32  = (float*)   (ws + 40230656);     //     12,288
    float*    bfc2_32  = (float*)   (ws + 40242944);     //      3,072
    double*   q0_64    = (double*)  (ws + 40246016);     //    393,216
    double*   wq0_64   = (double*)  (ws + 40639232);     //  4,718,592
    double*   vnorm2   = (double*)  (ws + 45357824);     //    100,864
    double*   cls64    = (double*)  (ws + 45458688);     //  1,210,368
    double*   score64  = (double*)  (ws + 46669056);     //    100,352
    int*      srctok   = (int*)     (ws + 46769408);     //     50,432
    // big slots (lifetime-sequenced):
    // SL1 [48.0M, 125.46M): xn64 (1-5) -> attn bf16 (6-8) -> act bf16 (11-12)
    double*   xn64     = (double*)  (ws + 48000000);     // 77,463,552
    bf16*     attn     = (bf16*)    (ws + 48000000);     // 59,610,624
    bf16*     act      = (bf16*)    (ws + 48000000);     // 77,463,552
    // SL2 [125.46M, 164.20M): xn hi/lo (1-3) -> v32 (4-8)
    ushort_t* xn_h     = (ushort_t*)(ws + 125463552);    // 19,365,888
    ushort_t* xn_l     = (ushort_t*)(ws + 144829440);    // 19,365,888
    float*    v32      = (float*)   (ws + 125463552);    // 38,731,776
    // SL3 [164.20M, 202.93M): q32 (3-6) -> xo hi/lo (8-9) -> h1 hi/lo (10-11)
    float*    q32      = (float*)   (ws + 164195328);    // 38,731,776
    ushort_t* xo_h     = (ushort_t*)(ws + 164195328);    // 19,365,888
    ushort_t* xo_l     = (ushort_t*)(ws + 183561216);    // 19,365,888
    ushort_t* h1_h     = (ushort_t*)(ws + 164195328);    // 19,365,888
    ushort_t* h1_l     = (ushort_t*)(ws + 183561216);    // 19,365,888
    // SL4 [202.93M, 241.66M): k32 (3-6) -> x2 (9-12)
    float*    k32      = (float*)   (ws + 202927104);    // 38,731,776
    float*    x2_32    = (float*)   (ws + 202927104);    // 38,731,776

    const dim3 blk(256);

    // 0) dtype detect + conversions
    detect_kernel<<<1, blk, 0, stream>>>((const ushort_t*)d_in[2], flag);
    cvt64_kernel<<<1024, blk, 0, stream>>>(d_in[2],  w64,     C_ * C3_, flag);
    tsplit_kernel<<<dim3(48, 24), blk, 0, stream>>>(d_in[2],  C_,  C3_, wqkvT_h, wqkvT_l, flag);
    tsplit_kernel<<<dim3(24, 24), blk, 0, stream>>>(d_in[3],  C_,  C_,  wprojT_h, wprojT_l, flag);
    tsplit_kernel<<<dim3(96, 24), blk, 0, stream>>>(d_in[9],  C_,  C4_, wfc1T_h, wfc1T_l, flag);
    tsplit_kernel<<<dim3(24, 96), blk, 0, stream>>>(d_in[11], C4_, C_,  wfc2T_h, wfc2T_l, flag);
    cvt32_kernel<<<3,  blk, 0, stream>>>(d_in[4],  bproj32, C_,  flag);
    cvt64_kernel<<<3,  blk, 0, stream>>>(d_in[5],  g1_64,   C_,  flag);
    cvt64_kernel<<<3,  blk, 0, stream>>>(d_in[6],  b1_64,   C_,  flag);
    cvt32_kernel<<<3,  blk, 0, stream>>>(d_in[7],  g2_32,   C_,  flag);
    cvt32_kernel<<<3,  blk, 0, stream>>>(d_in[8],  b2_32,   C_,  flag);
    cvt32_kernel<<<12, blk, 0, stream>>>(d_in[10], bfc1_32, C4_, flag);
    cvt32_kernel<<<3,  blk, 0, stream>>>(d_in[12], bfc2_32, C_,  flag);
    cvt64_kernel<<<50, blk, 0, stream>>>(d_in[1],  pol64,   M_,  flag);
    zero64_kernel<<<50, blk, 0, stream>>>(vnorm2, M_);

    // 1) LN1 fp64 (+ split copy)
    ln64_kernel<<<M_, blk, 0, stream>>>(d_in[0], g1_64, b1_64, xn64, xn_h, xn_l, flag);

    // 2) fp64 score-path precursors
    q0_kernel<<<B_, blk, 0, stream>>>(xn64, w64, pol64, q0_64);
    wq0_kernel<<<B_, blk, 0, stream>>>(w64, q0_64, wq0_64);

    // 3) q,k via split-bf16 MFMA GEMM
    { Epi e = {}; e.qq = q32; e.kk = k32; e.pol = pol64;
      mgemm<0, true><<<dim3(12, 99), blk, 0, stream>>>(xn_h, xn_l, wqkvT_h, wqkvT_l, M_, C_, e); }

    // 4) v fp64 GEMM (decision path) -> v32 + vnorm2 (overwrites xn split)
    gemm64_v<<<dim3(C_ / 64, M_ / 64), blk, 0, stream>>>(xn64, w64, pol64, v32, vnorm2);

    // 5) cls rows fp64 (last use of xn64)
    cls_kernel<<<B_, blk, 0, stream>>>(xn64, wq0_64, pol64, cls64);

    // 6) attention probs (writes SL1 over dead xn64)
    attn_kernel<<<BH_, blk, 0, stream>>>(q32, k32, pol64, attn);

    // 7) score + sampling
    score_kernel<<<B_, blk, 0, stream>>>(cls64, vnorm2, score64);
    sample_kernel<<<B_, blk, 0, stream>>>(score64, srctok);

    // 8) xo = gathered attn @ v -> split (SL3 over dead q32)
    av_kernel<<<BH_, blk, 0, stream>>>(attn, v32, srctok, xo_h, xo_l);

    // 9) proj MFMA -> x2 (SL4 over dead k32)
    { Epi e = {}; e.bias = bproj32; e.srctok = srctok; e.xin = d_in[0]; e.x2out = x2_32; e.flagp = flag;
      mgemm<1, true><<<dim3(6, 99), blk, 0, stream>>>(xo_h, xo_l, wprojT_h, wprojT_l, M_, C_, e); }

    // 10) LN2 fp32 -> h1 split (SL3 over dead xo)
    ln32_kernel<<<M_, blk, 0, stream>>>(x2_32, g2_32, b2_32, h1_h, h1_l);

    // 11) fc1 MFMA + GELU -> act bf16 (SL1 over dead attn)
    { Epi e = {}; e.bias = bfc1_32; e.act = act;
      mgemm<2, true><<<dim3(24, 99), blk, 0, stream>>>(h1_h, h1_l, wfc1T_h, wfc1T_l, M_, C_, e); }

    // 12) fc2 MFMA (bf16 act as A-hi) + residual + pol -> out
    { Epi e = {}; e.bias = bfc2_32; e.srctok = srctok; e.x2in = x2_32; e.dout = d_out; e.flagp = flag;
      mgemm<3, false><<<dim3(6, 99), blk, 0, stream>>>((const ushort_t*)act, nullptr, wfc2T_h, wfc2T_l, M_, C4_, e); }
}